// Round 1
// baseline (415.421 us; speedup 1.0000x reference)
//
#include <hip/hip_runtime.h>

#define N_NODES 10000
#define N_EDGES 320000
#define EL (N_EDGES + N_NODES)
#define HC 256

// ---------------- CSR build ----------------

__global__ void hist_kernel(const int* __restrict__ edges, int* __restrict__ cnt) {
  int e = blockIdx.x * blockDim.x + threadIdx.x;
  if (e >= EL) return;
  int d = (e < N_EDGES) ? edges[N_EDGES + e] : (e - N_EDGES);
  atomicAdd(&cnt[d], 1);
}

__global__ void scan_kernel(const int* __restrict__ cnt, int* __restrict__ off) {
  __shared__ int sums[1024];
  const int CH = 10;  // 1024*10 >= 10000
  int t = threadIdx.x;
  int base = t * CH;
  int local[CH];
  int run = 0;
#pragma unroll
  for (int i = 0; i < CH; ++i) {
    int idx = base + i;
    int v = (idx < N_NODES) ? cnt[idx] : 0;
    local[i] = run;
    run += v;
  }
  sums[t] = run;
  __syncthreads();
  for (int d = 1; d < 1024; d <<= 1) {
    int v = (t >= d) ? sums[t - d] : 0;
    __syncthreads();
    sums[t] += v;
    __syncthreads();
  }
  int pre = (t > 0) ? sums[t - 1] : 0;
#pragma unroll
  for (int i = 0; i < CH; ++i) {
    int idx = base + i;
    if (idx < N_NODES) off[idx] = pre + local[i];
  }
  if (t == 1023) off[N_NODES] = sums[1023];
}

__global__ void scatter_kernel(const int* __restrict__ edges, const int* __restrict__ off,
                               int* __restrict__ tmp, int* __restrict__ ssrc) {
  int e = blockIdx.x * blockDim.x + threadIdx.x;
  if (e >= EL) return;
  int s, d;
  if (e < N_EDGES) { s = edges[e]; d = edges[N_EDGES + e]; }
  else { s = d = e - N_EDGES; }
  int pos = off[d] + atomicAdd(&tmp[d], 1);
  ssrc[pos] = s;
}

// ---------------- GEMM: C[M,NCOLS] = A[M,K] @ B[K,NCOLS] (+bias)(+relu) ----------------
// EPI: 0 = none, 1 = bias, 2 = bias+relu

template <int K, int NCOLS, int EPI>
__global__ __launch_bounds__(256) void gemm_kernel(const float* __restrict__ A,
                                                   const float* __restrict__ B,
                                                   const float* __restrict__ bias,
                                                   float* __restrict__ C, int M) {
  constexpr int BM = 32, BK = 32;
  constexpr int CPT = NCOLS / 64;  // cols per thread
  __shared__ float As[BM][BK + 4];
  __shared__ float Bs[BK][NCOLS];
  int tid = threadIdx.x;
  int row0 = blockIdx.x * BM;
  int g = tid >> 6;       // wave id -> row group (8 rows each)
  int lane = tid & 63;
  int colBase = lane * CPT;

  float acc[8][CPT];
#pragma unroll
  for (int r = 0; r < 8; ++r)
#pragma unroll
    for (int j = 0; j < CPT; ++j) acc[r][j] = 0.f;

  for (int k0 = 0; k0 < K; k0 += BK) {
    // stage A tile (32x32), float4 per thread
    {
      int r = tid >> 3;
      int kc = (tid & 7) << 2;
      int grow = row0 + r;
      float4 av = make_float4(0.f, 0.f, 0.f, 0.f);
      if (grow < M) av = *(const float4*)(A + (size_t)grow * K + k0 + kc);
      *(float4*)&As[r][kc] = av;
    }
    // stage B tile (32 x NCOLS)
    {
      constexpr int PT = BK * NCOLS / 1024;  // float4s per thread
#pragma unroll
      for (int i = 0; i < PT; ++i) {
        int idx = (i * 256 + tid) * 4;
        int kk = idx / NCOLS;
        int cc = idx % NCOLS;
        *(float4*)&Bs[kk][cc] = *(const float4*)(B + (size_t)(k0 + kk) * NCOLS + cc);
      }
    }
    __syncthreads();
#pragma unroll
    for (int kk = 0; kk < BK; kk += 4) {
      float a4[8][4];
#pragma unroll
      for (int rr = 0; rr < 8; ++rr) {
        float4 t = *(const float4*)&As[g * 8 + rr][kk];
        a4[rr][0] = t.x; a4[rr][1] = t.y; a4[rr][2] = t.z; a4[rr][3] = t.w;
      }
      float b4[4][CPT];
#pragma unroll
      for (int u = 0; u < 4; ++u) {
        if constexpr (CPT == 4) {
          float4 t = *(const float4*)&Bs[kk + u][colBase];
          b4[u][0] = t.x; b4[u][1] = t.y; b4[u][2] = t.z; b4[u][3] = t.w;
        } else if constexpr (CPT == 2) {
          float2 t = *(const float2*)&Bs[kk + u][colBase];
          b4[u][0] = t.x; b4[u][1] = t.y;
        } else {
          b4[u][0] = Bs[kk + u][colBase];
        }
      }
#pragma unroll
      for (int u = 0; u < 4; ++u)
#pragma unroll
        for (int rr = 0; rr < 8; ++rr)
#pragma unroll
          for (int j = 0; j < CPT; ++j) acc[rr][j] += a4[rr][u] * b4[u][j];
    }
    __syncthreads();
  }

#pragma unroll
  for (int rr = 0; rr < 8; ++rr) {
    int row = row0 + g * 8 + rr;
    if (row >= M) continue;
#pragma unroll
    for (int j = 0; j < CPT; ++j) {
      float v = acc[rr][j];
      if constexpr (EPI >= 1) v += bias[colBase + j];
      if constexpr (EPI == 2) v = fmaxf(v, 0.f);
      C[(size_t)row * NCOLS + colBase + j] = v;
    }
  }
}

// ---------------- attention coefficients: asrc[n][h], adst[n][h] ----------------

__global__ __launch_bounds__(256) void attn_kernel(const float* __restrict__ xl,
                                                   const float* __restrict__ att_src,
                                                   const float* __restrict__ att_dst,
                                                   float4* __restrict__ asrc4,
                                                   float4* __restrict__ adst4) {
  int w = threadIdx.x >> 6, lane = threadIdx.x & 63;
  int n = blockIdx.x * 4 + w;
  if (n >= N_NODES) return;
  const float* xr = xl + (size_t)n * HC;
  float ps[4], pd[4];
#pragma unroll
  for (int h = 0; h < 4; ++h) {
    float v = xr[h * 64 + lane];
    ps[h] = v * att_src[h * 64 + lane];
    pd[h] = v * att_dst[h * 64 + lane];
  }
#pragma unroll
  for (int m = 32; m >= 1; m >>= 1) {
#pragma unroll
    for (int h = 0; h < 4; ++h) {
      ps[h] += __shfl_xor(ps[h], m);
      pd[h] += __shfl_xor(pd[h], m);
    }
  }
  if (lane == 0) {
    asrc4[n] = make_float4(ps[0], ps[1], ps[2], ps[3]);
    adst4[n] = make_float4(pd[0], pd[1], pd[2], pd[3]);
  }
}

// ---------------- fused GAT aggregation + bias + ELU + residual + LayerNorm ----------------
// MODE 0: residual is h0 (64-dim, zero-padded into head 0); MODE 1: residual is full 256-dim

template <int MODE>
__global__ __launch_bounds__(256) void agg_kernel(
    const int* __restrict__ off, const int* __restrict__ ssrc,
    const float4* __restrict__ asrc4, const float4* __restrict__ adst4,
    const float* __restrict__ xl, const float* __restrict__ bias,
    const float* __restrict__ resid, const float* __restrict__ ln_g,
    const float* __restrict__ ln_b, float* __restrict__ hout) {
  int w = threadIdx.x >> 6, lane = threadIdx.x & 63;
  int n = blockIdx.x * 4 + w;
  if (n >= N_NODES) return;
  float4 ad = adst4[n];
  float acc[4] = {0.f, 0.f, 0.f, 0.f};
  float wsum[4] = {0.f, 0.f, 0.f, 0.f};
  int e1 = off[n + 1];
  for (int i = off[n]; i < e1; ++i) {
    int s = ssrc[i];
    float4 as = asrc4[s];
    float e0 = as.x + ad.x, ee1 = as.y + ad.y, e2 = as.z + ad.z, e3 = as.w + ad.w;
    e0 = e0 > 0.f ? e0 : 0.2f * e0;
    ee1 = ee1 > 0.f ? ee1 : 0.2f * ee1;
    e2 = e2 > 0.f ? e2 : 0.2f * e2;
    e3 = e3 > 0.f ? e3 : 0.2f * e3;
    float w0 = expf(e0), w1 = expf(ee1), w2 = expf(e2), w3 = expf(e3);
    const float* xr = xl + (size_t)s * HC + lane;
    acc[0] += w0 * xr[0];
    acc[1] += w1 * xr[64];
    acc[2] += w2 * xr[128];
    acc[3] += w3 * xr[192];
    wsum[0] += w0; wsum[1] += w1; wsum[2] += w2; wsum[3] += w3;
  }
  float v[4];
#pragma unroll
  for (int h = 0; h < 4; ++h) v[h] = acc[h] / wsum[h] + bias[h * 64 + lane];
#pragma unroll
  for (int h = 0; h < 4; ++h) v[h] = v[h] > 0.f ? v[h] : expf(v[h]) - 1.f;
  if constexpr (MODE == 0) {
    v[0] += resid[(size_t)n * 64 + lane];
  } else {
#pragma unroll
    for (int h = 0; h < 4; ++h) v[h] += resid[(size_t)n * HC + h * 64 + lane];
  }
  float s1 = v[0] + v[1] + v[2] + v[3];
  float s2 = v[0] * v[0] + v[1] * v[1] + v[2] * v[2] + v[3] * v[3];
#pragma unroll
  for (int m = 32; m >= 1; m >>= 1) {
    s1 += __shfl_xor(s1, m);
    s2 += __shfl_xor(s2, m);
  }
  float mean = s1 * (1.f / 256.f);
  float var = s2 * (1.f / 256.f) - mean * mean;
  float inv = rsqrtf(var + 1e-5f);
#pragma unroll
  for (int h = 0; h < 4; ++h) {
    int c = h * 64 + lane;
    hout[(size_t)n * HC + c] = (v[h] - mean) * inv * ln_g[c] + ln_b[c];
  }
}

// ---------------- launch ----------------

extern "C" void kernel_launch(void* const* d_in, const int* in_sizes, int n_in,
                              void* d_out, int out_size, void* d_ws, size_t ws_size,
                              hipStream_t stream) {
  (void)in_sizes; (void)n_in; (void)out_size; (void)ws_size;
  const float* x      = (const float*)d_in[0];
  const int*   edges  = (const int*)d_in[1];
  const float* lin_w  = (const float*)d_in[2];
  const float* lin_b  = (const float*)d_in[3];
  const float* gat_w[3] = {(const float*)d_in[4], (const float*)d_in[10], (const float*)d_in[16]};
  const float* att_s[3] = {(const float*)d_in[5], (const float*)d_in[11], (const float*)d_in[17]};
  const float* att_d[3] = {(const float*)d_in[6], (const float*)d_in[12], (const float*)d_in[18]};
  const float* gat_b[3] = {(const float*)d_in[7], (const float*)d_in[13], (const float*)d_in[19]};
  const float* ln_g[3]  = {(const float*)d_in[8], (const float*)d_in[14], (const float*)d_in[20]};
  const float* ln_b[3]  = {(const float*)d_in[9], (const float*)d_in[15], (const float*)d_in[21]};
  const float* ffn_w1 = (const float*)d_in[22];
  const float* ffn_b1 = (const float*)d_in[23];
  const float* ffn_w2 = (const float*)d_in[24];
  const float* ffn_b2 = (const float*)d_in[25];

  char* p = (char*)d_ws;
  auto alloc = [&](size_t bytes) {
    char* q = p;
    p += (bytes + 255) & ~(size_t)255;
    return q;
  };
  int* off   = (int*)alloc((N_NODES + 1) * 4);
  int* cnt   = (int*)alloc(N_NODES * 4);
  int* ssrc  = (int*)alloc((size_t)EL * 4);
  float* h0  = (float*)alloc((size_t)N_NODES * 64 * 4);
  float* hA  = (float*)alloc((size_t)N_NODES * HC * 4);
  float* hB  = (float*)alloc((size_t)N_NODES * HC * 4);
  float* xl  = (float*)alloc((size_t)N_NODES * HC * 4);
  float* as4 = (float*)alloc((size_t)N_NODES * 16);
  float* ad4 = (float*)alloc((size_t)N_NODES * 16);
  float* mid = xl;  // alias: xl dead by FFN time; mid needs N*128 <= N*256

  // CSR build (deterministic up to within-segment order; only affects fp sum order)
  hipMemsetAsync(cnt, 0, N_NODES * 4, stream);
  hist_kernel<<<(EL + 255) / 256, 256, 0, stream>>>(edges, cnt);
  scan_kernel<<<1, 1024, 0, stream>>>(cnt, off);
  hipMemsetAsync(cnt, 0, N_NODES * 4, stream);
  scatter_kernel<<<(EL + 255) / 256, 256, 0, stream>>>(edges, off, cnt, ssrc);

  const int gblk = (N_NODES + 31) / 32;
  const int nblk = (N_NODES + 3) / 4;

  // h0 = relu(x @ lin_w + lin_b)
  gemm_kernel<64, 64, 2><<<gblk, 256, 0, stream>>>(x, lin_w, lin_b, h0, N_NODES);

  // layer 0 (in: h0 64-dim, residual pad)
  gemm_kernel<64, 256, 0><<<gblk, 256, 0, stream>>>(h0, gat_w[0], nullptr, xl, N_NODES);
  attn_kernel<<<nblk, 256, 0, stream>>>(xl, att_s[0], att_d[0], (float4*)as4, (float4*)ad4);
  agg_kernel<0><<<nblk, 256, 0, stream>>>(off, ssrc, (const float4*)as4, (const float4*)ad4,
                                          xl, gat_b[0], h0, ln_g[0], ln_b[0], hA);
  // layer 1
  gemm_kernel<256, 256, 0><<<gblk, 256, 0, stream>>>(hA, gat_w[1], nullptr, xl, N_NODES);
  attn_kernel<<<nblk, 256, 0, stream>>>(xl, att_s[1], att_d[1], (float4*)as4, (float4*)ad4);
  agg_kernel<1><<<nblk, 256, 0, stream>>>(off, ssrc, (const float4*)as4, (const float4*)ad4,
                                          xl, gat_b[1], hA, ln_g[1], ln_b[1], hB);
  // layer 2
  gemm_kernel<256, 256, 0><<<gblk, 256, 0, stream>>>(hB, gat_w[2], nullptr, xl, N_NODES);
  attn_kernel<<<nblk, 256, 0, stream>>>(xl, att_s[2], att_d[2], (float4*)as4, (float4*)ad4);
  agg_kernel<1><<<nblk, 256, 0, stream>>>(off, ssrc, (const float4*)as4, (const float4*)ad4,
                                          xl, gat_b[2], hB, ln_g[2], ln_b[2], hA);

  // FFN: out = relu(hA @ w1 + b1) @ w2 + b2
  gemm_kernel<256, 128, 2><<<gblk, 256, 0, stream>>>(hA, ffn_w1, ffn_b1, mid, N_NODES);
  gemm_kernel<128, 64, 1><<<gblk, 256, 0, stream>>>(mid, ffn_w2, ffn_b2, (float*)d_out, N_NODES);
}

// Round 3
// 369.490 us; speedup vs baseline: 1.1243x; 1.1243x over previous
//
#include <hip/hip_runtime.h>

#define N_NODES 10000
#define N_EDGES 320000
#define EL (N_EDGES + N_NODES)
#define HC 256

// ---------------- CSR build ----------------

__global__ void hist_kernel(const int* __restrict__ edges, int* __restrict__ cnt) {
  int e = blockIdx.x * blockDim.x + threadIdx.x;
  if (e >= EL) return;
  int d = (e < N_EDGES) ? edges[N_EDGES + e] : (e - N_EDGES);
  atomicAdd(&cnt[d], 1);
}

__global__ void scan_kernel(const int* __restrict__ cnt, int* __restrict__ off) {
  __shared__ int sums[1024];
  const int CH = 10;  // 1024*10 >= 10000
  int t = threadIdx.x;
  int base = t * CH;
  int local[CH];
  int run = 0;
#pragma unroll
  for (int i = 0; i < CH; ++i) {
    int idx = base + i;
    int v = (idx < N_NODES) ? cnt[idx] : 0;
    local[i] = run;
    run += v;
  }
  sums[t] = run;
  __syncthreads();
  for (int d = 1; d < 1024; d <<= 1) {
    int v = (t >= d) ? sums[t - d] : 0;
    __syncthreads();
    sums[t] += v;
    __syncthreads();
  }
  int pre = (t > 0) ? sums[t - 1] : 0;
#pragma unroll
  for (int i = 0; i < CH; ++i) {
    int idx = base + i;
    if (idx < N_NODES) off[idx] = pre + local[i];
  }
  if (t == 1023) off[N_NODES] = sums[1023];
}

__global__ void scatter_kernel(const int* __restrict__ edges, const int* __restrict__ off,
                               int* __restrict__ tmp, int* __restrict__ ssrc) {
  int e = blockIdx.x * blockDim.x + threadIdx.x;
  if (e >= EL) return;
  int s, d;
  if (e < N_EDGES) { s = edges[e]; d = edges[N_EDGES + e]; }
  else { s = d = e - N_EDGES; }
  int pos = off[d] + atomicAdd(&tmp[d], 1);
  ssrc[pos] = s;
}

// ---------------- GEMM: C[M,NCOLS] = A[M,K] @ B[K,NCOLS] (+bias)(+relu) ----------------
// EPI: 0 = none, 1 = bias, 2 = bias+relu

template <int K, int NCOLS, int EPI>
__global__ __launch_bounds__(256) void gemm_kernel(const float* __restrict__ A,
                                                   const float* __restrict__ B,
                                                   const float* __restrict__ bias,
                                                   float* __restrict__ C, int M) {
  constexpr int BM = 32, BK = 32;
  constexpr int CPT = NCOLS / 64;  // cols per thread
  __shared__ float As[BM][BK + 4];
  __shared__ float Bs[BK][NCOLS];
  int tid = threadIdx.x;
  int row0 = blockIdx.x * BM;
  int g = tid >> 6;       // wave id -> row group (8 rows each)
  int lane = tid & 63;
  int colBase = lane * CPT;

  float acc[8][CPT];
#pragma unroll
  for (int r = 0; r < 8; ++r)
#pragma unroll
    for (int j = 0; j < CPT; ++j) acc[r][j] = 0.f;

  for (int k0 = 0; k0 < K; k0 += BK) {
    // stage A tile (32x32), float4 per thread
    {
      int r = tid >> 3;
      int kc = (tid & 7) << 2;
      int grow = row0 + r;
      float4 av = make_float4(0.f, 0.f, 0.f, 0.f);
      if (grow < M) av = *(const float4*)(A + (size_t)grow * K + k0 + kc);
      *(float4*)&As[r][kc] = av;
    }
    // stage B tile (32 x NCOLS)
    {
      constexpr int PT = BK * NCOLS / 1024;  // float4s per thread
#pragma unroll
      for (int i = 0; i < PT; ++i) {
        int idx = (i * 256 + tid) * 4;
        int kk = idx / NCOLS;
        int cc = idx % NCOLS;
        *(float4*)&Bs[kk][cc] = *(const float4*)(B + (size_t)(k0 + kk) * NCOLS + cc);
      }
    }
    __syncthreads();
#pragma unroll
    for (int kk = 0; kk < BK; kk += 4) {
      float a4[8][4];
#pragma unroll
      for (int rr = 0; rr < 8; ++rr) {
        float4 t = *(const float4*)&As[g * 8 + rr][kk];
        a4[rr][0] = t.x; a4[rr][1] = t.y; a4[rr][2] = t.z; a4[rr][3] = t.w;
      }
      float b4[4][CPT];
#pragma unroll
      for (int u = 0; u < 4; ++u) {
        if constexpr (CPT == 4) {
          float4 t = *(const float4*)&Bs[kk + u][colBase];
          b4[u][0] = t.x; b4[u][1] = t.y; b4[u][2] = t.z; b4[u][3] = t.w;
        } else if constexpr (CPT == 2) {
          float2 t = *(const float2*)&Bs[kk + u][colBase];
          b4[u][0] = t.x; b4[u][1] = t.y;
        } else {
          b4[u][0] = Bs[kk + u][colBase];
        }
      }
#pragma unroll
      for (int u = 0; u < 4; ++u)
#pragma unroll
        for (int rr = 0; rr < 8; ++rr)
#pragma unroll
          for (int j = 0; j < CPT; ++j) acc[rr][j] += a4[rr][u] * b4[u][j];
    }
    __syncthreads();
  }

#pragma unroll
  for (int rr = 0; rr < 8; ++rr) {
    int row = row0 + g * 8 + rr;
    if (row >= M) continue;
#pragma unroll
    for (int j = 0; j < CPT; ++j) {
      float v = acc[rr][j];
      if constexpr (EPI >= 1) v += bias[colBase + j];
      if constexpr (EPI == 2) v = fmaxf(v, 0.f);
      C[(size_t)row * NCOLS + colBase + j] = v;
    }
  }
}

// ---------------- attention coefficients: asrc[n*4+h], adst[n*4+h] ----------------
// Lane l owns channels 4l..4l+3 (all in head l>>4); 16-lane-group reduce.

__global__ __launch_bounds__(256) void attn_kernel(const float* __restrict__ xl,
                                                   const float* __restrict__ att_src,
                                                   const float* __restrict__ att_dst,
                                                   float* __restrict__ asrc,
                                                   float* __restrict__ adst) {
  int w = threadIdx.x >> 6, lane = threadIdx.x & 63;
  int n = blockIdx.x * 4 + w;
  if (n >= N_NODES) return;
  float4 xv = *(const float4*)(xl + (size_t)n * HC + lane * 4);
  float4 s4 = *(const float4*)(att_src + lane * 4);
  float4 d4 = *(const float4*)(att_dst + lane * 4);
  float ps = xv.x * s4.x + xv.y * s4.y + xv.z * s4.z + xv.w * s4.w;
  float pd = xv.x * d4.x + xv.y * d4.y + xv.z * d4.z + xv.w * d4.w;
#pragma unroll
  for (int m = 8; m >= 1; m >>= 1) {
    ps += __shfl_xor(ps, m);
    pd += __shfl_xor(pd, m);
  }
  if ((lane & 15) == 0) {
    int h = lane >> 4;
    asrc[n * 4 + h] = ps;
    adst[n * 4 + h] = pd;
  }
}

// ---------------- fused GAT aggregation + bias + ELU + residual + LayerNorm ----------------
// Lane l owns channels 4l..4l+3 (head h = l>>4). One wave per dst node.
// MODE 0: residual is h0 (64-dim); MODE 1: residual is full 256-dim

template <int MODE>
__global__ __launch_bounds__(256) void agg_kernel(
    const int* __restrict__ off, const int* __restrict__ ssrc,
    const float* __restrict__ asrc, const float* __restrict__ adst,
    const float* __restrict__ xl, const float* __restrict__ bias,
    const float* __restrict__ resid, const float* __restrict__ ln_g,
    const float* __restrict__ ln_b, float* __restrict__ hout) {
  int w = threadIdx.x >> 6, lane = threadIdx.x & 63;
  int n = blockIdx.x * 4 + w;
  if (n >= N_NODES) return;
  int h = lane >> 4;
  float ad = adst[n * 4 + h];

  float4 acc = make_float4(0.f, 0.f, 0.f, 0.f);
  float wsum = 0.f;
  int i0 = off[n], e1 = off[n + 1];

  // software pipeline: prefetch next edge's src, attention coeff, and feature row
  int s = ssrc[i0];
  float as = asrc[s * 4 + h];
  float4 xv = *(const float4*)(xl + (size_t)s * HC + (lane << 2));
  for (int i = i0 + 1; i < e1; ++i) {
    int sn = ssrc[i];
    float asn = asrc[sn * 4 + h];
    float4 xn = *(const float4*)(xl + (size_t)sn * HC + (lane << 2));
    float e = as + ad;
    e = e > 0.f ? e : 0.2f * e;
    float wg = __expf(e);
    wsum += wg;
    acc.x = fmaf(wg, xv.x, acc.x);
    acc.y = fmaf(wg, xv.y, acc.y);
    acc.z = fmaf(wg, xv.z, acc.z);
    acc.w = fmaf(wg, xv.w, acc.w);
    as = asn;
    xv = xn;
  }
  {  // epilogue edge
    float e = as + ad;
    e = e > 0.f ? e : 0.2f * e;
    float wg = __expf(e);
    wsum += wg;
    acc.x = fmaf(wg, xv.x, acc.x);
    acc.y = fmaf(wg, xv.y, acc.y);
    acc.z = fmaf(wg, xv.z, acc.z);
    acc.w = fmaf(wg, xv.w, acc.w);
  }

  float rw = 1.f / wsum;
  float4 b4 = *(const float4*)(bias + lane * 4);
  float v0 = fmaf(acc.x, rw, b4.x);
  float v1 = fmaf(acc.y, rw, b4.y);
  float v2 = fmaf(acc.z, rw, b4.z);
  float v3 = fmaf(acc.w, rw, b4.w);
  v0 = v0 > 0.f ? v0 : __expf(v0) - 1.f;
  v1 = v1 > 0.f ? v1 : __expf(v1) - 1.f;
  v2 = v2 > 0.f ? v2 : __expf(v2) - 1.f;
  v3 = v3 > 0.f ? v3 : __expf(v3) - 1.f;

  if constexpr (MODE == 0) {
    if (lane < 16) {
      float4 r = *(const float4*)(resid + (size_t)n * 64 + lane * 4);
      v0 += r.x; v1 += r.y; v2 += r.z; v3 += r.w;
    }
  } else {
    float4 r = *(const float4*)(resid + (size_t)n * HC + lane * 4);
    v0 += r.x; v1 += r.y; v2 += r.z; v3 += r.w;
  }

  float s1 = v0 + v1 + v2 + v3;
  float s2 = v0 * v0 + v1 * v1 + v2 * v2 + v3 * v3;
#pragma unroll
  for (int m = 32; m >= 1; m >>= 1) {
    s1 += __shfl_xor(s1, m);
    s2 += __shfl_xor(s2, m);
  }
  float mean = s1 * (1.f / 256.f);
  float var = s2 * (1.f / 256.f) - mean * mean;
  float inv = rsqrtf(var + 1e-5f);

  float4 g4 = *(const float4*)(ln_g + lane * 4);
  float4 lb4 = *(const float4*)(ln_b + lane * 4);
  float4 o;
  o.x = (v0 - mean) * inv * g4.x + lb4.x;
  o.y = (v1 - mean) * inv * g4.y + lb4.y;
  o.z = (v2 - mean) * inv * g4.z + lb4.z;
  o.w = (v3 - mean) * inv * g4.w + lb4.w;
  *(float4*)(hout + (size_t)n * HC + lane * 4) = o;
}

// ---------------- launch ----------------

extern "C" void kernel_launch(void* const* d_in, const int* in_sizes, int n_in,
                              void* d_out, int out_size, void* d_ws, size_t ws_size,
                              hipStream_t stream) {
  (void)in_sizes; (void)n_in; (void)out_size; (void)ws_size;
  const float* x      = (const float*)d_in[0];
  const int*   edges  = (const int*)d_in[1];
  const float* lin_w  = (const float*)d_in[2];
  const float* lin_b  = (const float*)d_in[3];
  const float* gat_w[3] = {(const float*)d_in[4], (const float*)d_in[10], (const float*)d_in[16]};
  const float* att_s[3] = {(const float*)d_in[5], (const float*)d_in[11], (const float*)d_in[17]};
  const float* att_d[3] = {(const float*)d_in[6], (const float*)d_in[12], (const float*)d_in[18]};
  const float* gat_b[3] = {(const float*)d_in[7], (const float*)d_in[13], (const float*)d_in[19]};
  const float* ln_g[3]  = {(const float*)d_in[8], (const float*)d_in[14], (const float*)d_in[20]};
  const float* ln_b[3]  = {(const float*)d_in[9], (const float*)d_in[15], (const float*)d_in[21]};
  const float* ffn_w1 = (const float*)d_in[22];
  const float* ffn_b1 = (const float*)d_in[23];
  const float* ffn_w2 = (const float*)d_in[24];
  const float* ffn_b2 = (const float*)d_in[25];

  char* p = (char*)d_ws;
  auto alloc = [&](size_t bytes) {
    char* q = p;
    p += (bytes + 255) & ~(size_t)255;
    return q;
  };
  int* off   = (int*)alloc((N_NODES + 1) * 4);
  int* cnt   = (int*)alloc(N_NODES * 4);
  int* ssrc  = (int*)alloc((size_t)EL * 4);
  float* h0  = (float*)alloc((size_t)N_NODES * 64 * 4);
  float* hA  = (float*)alloc((size_t)N_NODES * HC * 4);
  float* hB  = (float*)alloc((size_t)N_NODES * HC * 4);
  float* xl  = (float*)alloc((size_t)N_NODES * HC * 4);
  float* as4 = (float*)alloc((size_t)N_NODES * 16);
  float* ad4 = (float*)alloc((size_t)N_NODES * 16);
  float* mid = xl;  // alias: xl dead by FFN time; mid needs N*128 <= N*256

  // CSR build (deterministic up to within-segment order; only affects fp sum order)
  hipMemsetAsync(cnt, 0, N_NODES * 4, stream);
  hist_kernel<<<(EL + 255) / 256, 256, 0, stream>>>(edges, cnt);
  scan_kernel<<<1, 1024, 0, stream>>>(cnt, off);
  hipMemsetAsync(cnt, 0, N_NODES * 4, stream);
  scatter_kernel<<<(EL + 255) / 256, 256, 0, stream>>>(edges, off, cnt, ssrc);

  const int gblk = (N_NODES + 31) / 32;
  const int nblk = (N_NODES + 3) / 4;

  // h0 = relu(x @ lin_w + lin_b)
  gemm_kernel<64, 64, 2><<<gblk, 256, 0, stream>>>(x, lin_w, lin_b, h0, N_NODES);

  // layer 0 (in: h0 64-dim, residual pad)
  gemm_kernel<64, 256, 0><<<gblk, 256, 0, stream>>>(h0, gat_w[0], nullptr, xl, N_NODES);
  attn_kernel<<<nblk, 256, 0, stream>>>(xl, att_s[0], att_d[0], as4, ad4);
  agg_kernel<0><<<nblk, 256, 0, stream>>>(off, ssrc, as4, ad4,
                                          xl, gat_b[0], h0, ln_g[0], ln_b[0], hA);
  // layer 1
  gemm_kernel<256, 256, 0><<<gblk, 256, 0, stream>>>(hA, gat_w[1], nullptr, xl, N_NODES);
  attn_kernel<<<nblk, 256, 0, stream>>>(xl, att_s[1], att_d[1], as4, ad4);
  agg_kernel<1><<<nblk, 256, 0, stream>>>(off, ssrc, as4, ad4,
                                          xl, gat_b[1], hA, ln_g[1], ln_b[1], hB);
  // layer 2
  gemm_kernel<256, 256, 0><<<gblk, 256, 0, stream>>>(hB, gat_w[2], nullptr, xl, N_NODES);
  attn_kernel<<<nblk, 256, 0, stream>>>(xl, att_s[2], att_d[2], as4, ad4);
  agg_kernel<1><<<nblk, 256, 0, stream>>>(off, ssrc, as4, ad4,
                                          xl, gat_b[2], hB, ln_g[2], ln_b[2], hA);

  // FFN: out = relu(hA @ w1 + b1) @ w2 + b2
  gemm_kernel<256, 128, 2><<<gblk, 256, 0, stream>>>(hA, ffn_w1, ffn_b1, mid, N_NODES);
  gemm_kernel<128, 64, 1><<<gblk, 256, 0, stream>>>(mid, ffn_w2, ffn_b2, (float*)d_out, N_NODES);
}

// Round 6
// 318.448 us; speedup vs baseline: 1.3045x; 1.1603x over previous
//
#include <hip/hip_runtime.h>

#define N_NODES 10000
#define N_EDGES 320000
#define EL (N_EDGES + N_NODES)
#define HC 256

// ---------------- CSR build ----------------

__global__ void hist_kernel(const int* __restrict__ edges, int* __restrict__ cnt) {
  int e = blockIdx.x * blockDim.x + threadIdx.x;
  if (e >= EL) return;
  int d = (e < N_EDGES) ? edges[N_EDGES + e] : (e - N_EDGES);
  atomicAdd(&cnt[d], 1);
}

__global__ void scan_kernel(const int* __restrict__ cnt, int* __restrict__ off) {
  __shared__ int sums[1024];
  const int CH = 10;  // 1024*10 >= 10000
  int t = threadIdx.x;
  int base = t * CH;
  int local[CH];
  int run = 0;
#pragma unroll
  for (int i = 0; i < CH; ++i) {
    int idx = base + i;
    int v = (idx < N_NODES) ? cnt[idx] : 0;
    local[i] = run;
    run += v;
  }
  sums[t] = run;
  __syncthreads();
  for (int d = 1; d < 1024; d <<= 1) {
    int v = (t >= d) ? sums[t - d] : 0;
    __syncthreads();
    sums[t] += v;
    __syncthreads();
  }
  int pre = (t > 0) ? sums[t - 1] : 0;
#pragma unroll
  for (int i = 0; i < CH; ++i) {
    int idx = base + i;
    if (idx < N_NODES) off[idx] = pre + local[i];
  }
  if (t == 1023) off[N_NODES] = sums[1023];
}

__global__ void scatter_kernel(const int* __restrict__ edges, const int* __restrict__ off,
                               int* __restrict__ tmp, int* __restrict__ ssrc) {
  int e = blockIdx.x * blockDim.x + threadIdx.x;
  if (e >= EL) return;
  int s, d;
  if (e < N_EDGES) { s = edges[e]; d = edges[N_EDGES + e]; }
  else { s = d = e - N_EDGES; }
  int pos = off[d] + atomicAdd(&tmp[d], 1);
  ssrc[pos] = s;
}

// ---------------- GEMM: C[M,NCOLS] = A[M,K] @ B[K,NCOLS] (+bias)(+relu)(+attn dots) ------
// EPI: 0 = none, 1 = bias, 2 = bias+relu
// ATTN: 1 = also compute per-head attention dots from acc (requires NCOLS==256)

template <int K, int NCOLS, int EPI, int ATTN>
__global__ __launch_bounds__(256) void gemm_kernel(const float* __restrict__ A,
                                                   const float* __restrict__ B,
                                                   const float* __restrict__ bias,
                                                   float* __restrict__ C, int M,
                                                   const float* __restrict__ att_src,
                                                   const float* __restrict__ att_dst,
                                                   float* __restrict__ asrc_out,
                                                   float* __restrict__ adst_out) {
  constexpr int BM = 32, BK = 32;
  constexpr int CPT = NCOLS / 64;  // cols per thread
  __shared__ float As[BM][BK + 4];
  __shared__ float Bs[BK][NCOLS];
  int tid = threadIdx.x;
  int row0 = blockIdx.x * BM;
  int g = tid >> 6;       // wave id -> row group (8 rows each)
  int lane = tid & 63;
  int colBase = lane * CPT;

  float acc[8][CPT];
#pragma unroll
  for (int r = 0; r < 8; ++r)
#pragma unroll
    for (int j = 0; j < CPT; ++j) acc[r][j] = 0.f;

  for (int k0 = 0; k0 < K; k0 += BK) {
    // stage A tile (32x32), float4 per thread
    {
      int r = tid >> 3;
      int kc = (tid & 7) << 2;
      int grow = row0 + r;
      float4 av = make_float4(0.f, 0.f, 0.f, 0.f);
      if (grow < M) av = *(const float4*)(A + (size_t)grow * K + k0 + kc);
      *(float4*)&As[r][kc] = av;
    }
    // stage B tile (32 x NCOLS)
    {
      constexpr int PT = BK * NCOLS / 1024;  // float4s per thread
#pragma unroll
      for (int i = 0; i < PT; ++i) {
        int idx = (i * 256 + tid) * 4;
        int kk = idx / NCOLS;
        int cc = idx % NCOLS;
        *(float4*)&Bs[kk][cc] = *(const float4*)(B + (size_t)(k0 + kk) * NCOLS + cc);
      }
    }
    __syncthreads();
#pragma unroll
    for (int kk = 0; kk < BK; kk += 4) {
      float a4[8][4];
#pragma unroll
      for (int rr = 0; rr < 8; ++rr) {
        float4 t = *(const float4*)&As[g * 8 + rr][kk];
        a4[rr][0] = t.x; a4[rr][1] = t.y; a4[rr][2] = t.z; a4[rr][3] = t.w;
      }
      float b4[4][CPT];
#pragma unroll
      for (int u = 0; u < 4; ++u) {
        if constexpr (CPT == 4) {
          float4 t = *(const float4*)&Bs[kk + u][colBase];
          b4[u][0] = t.x; b4[u][1] = t.y; b4[u][2] = t.z; b4[u][3] = t.w;
        } else if constexpr (CPT == 2) {
          float2 t = *(const float2*)&Bs[kk + u][colBase];
          b4[u][0] = t.x; b4[u][1] = t.y;
        } else {
          b4[u][0] = Bs[kk + u][colBase];
        }
      }
#pragma unroll
      for (int u = 0; u < 4; ++u)
#pragma unroll
        for (int rr = 0; rr < 8; ++rr)
#pragma unroll
          for (int j = 0; j < CPT; ++j) acc[rr][j] += a4[rr][u] * b4[u][j];
    }
    __syncthreads();
  }

  if constexpr (ATTN) {
    // lane owns channels lane*4..lane*4+3, all within head lane>>4.
    // asrc[row*4+h] = sum over head-h channels of xl[row][c]*att_src[c]
    float4 s4 = *(const float4*)(att_src + lane * 4);
    float4 d4 = *(const float4*)(att_dst + lane * 4);
#pragma unroll
    for (int rr = 0; rr < 8; ++rr) {
      int row = row0 + g * 8 + rr;
      float ps = acc[rr][0] * s4.x + acc[rr][1] * s4.y + acc[rr][2] * s4.z + acc[rr][3] * s4.w;
      float pd = acc[rr][0] * d4.x + acc[rr][1] * d4.y + acc[rr][2] * d4.z + acc[rr][3] * d4.w;
#pragma unroll
      for (int m = 8; m >= 1; m >>= 1) {
        ps += __shfl_xor(ps, m);
        pd += __shfl_xor(pd, m);
      }
      if (row < M && (lane & 15) == 0) {
        asrc_out[row * 4 + (lane >> 4)] = ps;
        adst_out[row * 4 + (lane >> 4)] = pd;
      }
    }
  }

#pragma unroll
  for (int rr = 0; rr < 8; ++rr) {
    int row = row0 + g * 8 + rr;
    if (row >= M) continue;
#pragma unroll
    for (int j = 0; j < CPT; ++j) {
      float v = acc[rr][j];
      if constexpr (EPI >= 1) v += bias[colBase + j];
      if constexpr (EPI == 2) v = fmaxf(v, 0.f);
      C[(size_t)row * NCOLS + colBase + j] = v;
    }
  }
}

// ---------------- fused GAT aggregation + bias + ELU + residual + LayerNorm ----------------
// Lane l owns channels 4l..4l+3 (head h = l>>4). One wave per dst node.
// Chunk-4 edge pipeline: ssrc prefetched 2 chunks ahead, asrc/xl 1 chunk ahead.
// MODE 0: residual is h0 (64-dim); MODE 1: residual is full 256-dim

template <int MODE>
__global__ __launch_bounds__(256) void agg_kernel(
    const int* __restrict__ off, const int* __restrict__ ssrc,
    const float* __restrict__ asrc, const float* __restrict__ adst,
    const float* __restrict__ xl, const float* __restrict__ bias,
    const float* __restrict__ resid, const float* __restrict__ ln_g,
    const float* __restrict__ ln_b, float* __restrict__ hout) {
  int w = threadIdx.x >> 6, lane = threadIdx.x & 63;
  int n = blockIdx.x * 4 + w;
  if (n >= N_NODES) return;
  int h = lane >> 4;
  int ch = lane << 2;
  float ad = adst[n * 4 + h];

  int i0 = off[n], i1 = off[n + 1];
  int last = i1 - 1;

  float4 acc = make_float4(0.f, 0.f, 0.f, 0.f);
  float wsum = 0.f;

  // prologue: chunk 0 s-values, then a/x for chunk 0, then chunk 1 s-values
  int sA[4];
#pragma unroll
  for (int j = 0; j < 4; ++j) sA[j] = ssrc[min(i0 + j, last)];
  float ca[4]; float4 cx[4];
#pragma unroll
  for (int j = 0; j < 4; ++j) {
    ca[j] = asrc[sA[j] * 4 + h];
    cx[j] = *(const float4*)(xl + (size_t)sA[j] * HC + ch);
  }
#pragma unroll
  for (int j = 0; j < 4; ++j) sA[j] = ssrc[min(i0 + 4 + j, last)];

#pragma unroll 2
  for (int base = i0; base < i1; base += 4) {
    // issue a/x for next chunk (sA resident: issued one iteration ago)
    float na[4]; float4 nx[4];
#pragma unroll
    for (int j = 0; j < 4; ++j) {
      na[j] = asrc[sA[j] * 4 + h];
      nx[j] = *(const float4*)(xl + (size_t)sA[j] * HC + ch);
    }
    // issue ssrc for chunk k+2
#pragma unroll
    for (int j = 0; j < 4; ++j) sA[j] = ssrc[min(base + 8 + j, last)];
    // process current chunk
#pragma unroll
    for (int j = 0; j < 4; ++j) {
      float e = ca[j] + ad;
      e = e > 0.f ? e : 0.2f * e;
      float wg = __expf(e);
      wg = (base + j < i1) ? wg : 0.f;
      wsum += wg;
      acc.x = fmaf(wg, cx[j].x, acc.x);
      acc.y = fmaf(wg, cx[j].y, acc.y);
      acc.z = fmaf(wg, cx[j].z, acc.z);
      acc.w = fmaf(wg, cx[j].w, acc.w);
    }
    // rotate
#pragma unroll
    for (int j = 0; j < 4; ++j) { ca[j] = na[j]; cx[j] = nx[j]; }
  }

  float rw = 1.f / wsum;
  float4 b4 = *(const float4*)(bias + ch);
  float v0 = fmaf(acc.x, rw, b4.x);
  float v1 = fmaf(acc.y, rw, b4.y);
  float v2 = fmaf(acc.z, rw, b4.z);
  float v3 = fmaf(acc.w, rw, b4.w);
  v0 = v0 > 0.f ? v0 : __expf(v0) - 1.f;
  v1 = v1 > 0.f ? v1 : __expf(v1) - 1.f;
  v2 = v2 > 0.f ? v2 : __expf(v2) - 1.f;
  v3 = v3 > 0.f ? v3 : __expf(v3) - 1.f;

  if constexpr (MODE == 0) {
    if (lane < 16) {
      float4 r = *(const float4*)(resid + (size_t)n * 64 + ch);
      v0 += r.x; v1 += r.y; v2 += r.z; v3 += r.w;
    }
  } else {
    float4 r = *(const float4*)(resid + (size_t)n * HC + ch);
    v0 += r.x; v1 += r.y; v2 += r.z; v3 += r.w;
  }

  float s1 = v0 + v1 + v2 + v3;
  float s2 = v0 * v0 + v1 * v1 + v2 * v2 + v3 * v3;
#pragma unroll
  for (int m = 32; m >= 1; m >>= 1) {
    s1 += __shfl_xor(s1, m);
    s2 += __shfl_xor(s2, m);
  }
  float mean = s1 * (1.f / 256.f);
  float var = s2 * (1.f / 256.f) - mean * mean;
  float inv = rsqrtf(var + 1e-5f);

  float4 g4 = *(const float4*)(ln_g + ch);
  float4 lb4 = *(const float4*)(ln_b + ch);
  float4 o;
  o.x = (v0 - mean) * inv * g4.x + lb4.x;
  o.y = (v1 - mean) * inv * g4.y + lb4.y;
  o.z = (v2 - mean) * inv * g4.z + lb4.z;
  o.w = (v3 - mean) * inv * g4.w + lb4.w;
  *(float4*)(hout + (size_t)n * HC + ch) = o;
}

// ---------------- launch ----------------

extern "C" void kernel_launch(void* const* d_in, const int* in_sizes, int n_in,
                              void* d_out, int out_size, void* d_ws, size_t ws_size,
                              hipStream_t stream) {
  (void)in_sizes; (void)n_in; (void)out_size; (void)ws_size;
  const float* x      = (const float*)d_in[0];
  const int*   edges  = (const int*)d_in[1];
  const float* lin_w  = (const float*)d_in[2];
  const float* lin_b  = (const float*)d_in[3];
  const float* gat_w[3] = {(const float*)d_in[4], (const float*)d_in[10], (const float*)d_in[16]};
  const float* att_s[3] = {(const float*)d_in[5], (const float*)d_in[11], (const float*)d_in[17]};
  const float* att_d[3] = {(const float*)d_in[6], (const float*)d_in[12], (const float*)d_in[18]};
  const float* gat_b[3] = {(const float*)d_in[7], (const float*)d_in[13], (const float*)d_in[19]};
  const float* ln_g[3]  = {(const float*)d_in[8], (const float*)d_in[14], (const float*)d_in[20]};
  const float* ln_b[3]  = {(const float*)d_in[9], (const float*)d_in[15], (const float*)d_in[21]};
  const float* ffn_w1 = (const float*)d_in[22];
  const float* ffn_b1 = (const float*)d_in[23];
  const float* ffn_w2 = (const float*)d_in[24];
  const float* ffn_b2 = (const float*)d_in[25];

  char* p = (char*)d_ws;
  auto alloc = [&](size_t bytes) {
    char* q = p;
    p += (bytes + 255) & ~(size_t)255;
    return q;
  };
  int* off   = (int*)alloc((N_NODES + 1) * 4);
  int* cnt   = (int*)alloc(N_NODES * 4);
  int* ssrc  = (int*)alloc((size_t)EL * 4);
  float* h0  = (float*)alloc((size_t)N_NODES * 64 * 4);
  float* hA  = (float*)alloc((size_t)N_NODES * HC * 4);
  float* hB  = (float*)alloc((size_t)N_NODES * HC * 4);
  float* xl  = (float*)alloc((size_t)N_NODES * HC * 4);
  float* as4 = (float*)alloc((size_t)N_NODES * 16);
  float* ad4 = (float*)alloc((size_t)N_NODES * 16);
  float* mid = xl;  // alias: xl dead by FFN time; mid needs N*128 <= N*256

  // CSR build (deterministic up to within-segment order; only affects fp sum order)
  hipMemsetAsync(cnt, 0, N_NODES * 4, stream);
  hist_kernel<<<(EL + 255) / 256, 256, 0, stream>>>(edges, cnt);
  scan_kernel<<<1, 1024, 0, stream>>>(cnt, off);
  hipMemsetAsync(cnt, 0, N_NODES * 4, stream);
  scatter_kernel<<<(EL + 255) / 256, 256, 0, stream>>>(edges, off, cnt, ssrc);

  const int gblk = (N_NODES + 31) / 32;
  const int nblk = (N_NODES + 3) / 4;

  // h0 = relu(x @ lin_w + lin_b)
  gemm_kernel<64, 64, 2, 0><<<gblk, 256, 0, stream>>>(x, lin_w, lin_b, h0, N_NODES,
                                                      nullptr, nullptr, nullptr, nullptr);

  // layer 0 (in: h0 64-dim, residual pad); attn dots fused in GEMM epilogue
  gemm_kernel<64, 256, 0, 1><<<gblk, 256, 0, stream>>>(h0, gat_w[0], nullptr, xl, N_NODES,
                                                       att_s[0], att_d[0], as4, ad4);
  agg_kernel<0><<<nblk, 256, 0, stream>>>(off, ssrc, as4, ad4,
                                          xl, gat_b[0], h0, ln_g[0], ln_b[0], hA);
  // layer 1
  gemm_kernel<256, 256, 0, 1><<<gblk, 256, 0, stream>>>(hA, gat_w[1], nullptr, xl, N_NODES,
                                                        att_s[1], att_d[1], as4, ad4);
  agg_kernel<1><<<nblk, 256, 0, stream>>>(off, ssrc, as4, ad4,
                                          xl, gat_b[1], hA, ln_g[1], ln_b[1], hB);
  // layer 2
  gemm_kernel<256, 256, 0, 1><<<gblk, 256, 0, stream>>>(hB, gat_w[2], nullptr, xl, N_NODES,
                                                        att_s[2], att_d[2], as4, ad4);
  agg_kernel<1><<<nblk, 256, 0, stream>>>(off, ssrc, as4, ad4,
                                          xl, gat_b[2], hB, ln_g[2], ln_b[2], hA);

  // FFN: out = relu(hA @ w1 + b1) @ w2 + b2
  gemm_kernel<256, 128, 2, 0><<<gblk, 256, 0, stream>>>(hA, ffn_w1, ffn_b1, mid, N_NODES,
                                                        nullptr, nullptr, nullptr, nullptr);
  gemm_kernel<128, 64, 1, 0><<<gblk, 256, 0, stream>>>(mid, ffn_w2, ffn_b2, (float*)d_out, N_NODES,
                                                       nullptr, nullptr, nullptr, nullptr);
}

// Round 7
// 316.907 us; speedup vs baseline: 1.3109x; 1.0049x over previous
//
#include <hip/hip_runtime.h>

#define N_NODES 10000
#define N_EDGES 320000
#define EL (N_EDGES + N_NODES)
#define HC 256

// ---------------- CSR build ----------------

// one cheap dispatch zeroing both counter arrays (rocclr fillBuffer costs ~40us each!)
__global__ void zero_kernel(int* __restrict__ cnt, int* __restrict__ cnt2) {
  int i = blockIdx.x * blockDim.x + threadIdx.x;
  if (i < N_NODES) { cnt[i] = 0; cnt2[i] = 0; }
}

__global__ void hist_kernel(const int* __restrict__ edges, int* __restrict__ cnt) {
  int e = blockIdx.x * blockDim.x + threadIdx.x;
  if (e >= EL) return;
  int d = (e < N_EDGES) ? edges[N_EDGES + e] : (e - N_EDGES);
  atomicAdd(&cnt[d], 1);
}

__global__ void scan_kernel(const int* __restrict__ cnt, int* __restrict__ off) {
  __shared__ int sums[1024];
  const int CH = 10;  // 1024*10 >= 10000
  int t = threadIdx.x;
  int base = t * CH;
  int local[CH];
  int run = 0;
#pragma unroll
  for (int i = 0; i < CH; ++i) {
    int idx = base + i;
    int v = (idx < N_NODES) ? cnt[idx] : 0;
    local[i] = run;
    run += v;
  }
  sums[t] = run;
  __syncthreads();
  for (int d = 1; d < 1024; d <<= 1) {
    int v = (t >= d) ? sums[t - d] : 0;
    __syncthreads();
    sums[t] += v;
    __syncthreads();
  }
  int pre = (t > 0) ? sums[t - 1] : 0;
#pragma unroll
  for (int i = 0; i < CH; ++i) {
    int idx = base + i;
    if (idx < N_NODES) off[idx] = pre + local[i];
  }
  if (t == 1023) off[N_NODES] = sums[1023];
}

__global__ void scatter_kernel(const int* __restrict__ edges, const int* __restrict__ off,
                               int* __restrict__ tmp, int* __restrict__ ssrc) {
  int e = blockIdx.x * blockDim.x + threadIdx.x;
  if (e >= EL) return;
  int s, d;
  if (e < N_EDGES) { s = edges[e]; d = edges[N_EDGES + e]; }
  else { s = d = e - N_EDGES; }
  int pos = off[d] + atomicAdd(&tmp[d], 1);
  ssrc[pos] = s;
}

// ---------------- GEMM: C[M,NCOLS] = A[M,K] @ B[K,NCOLS] (+bias)(+relu)(+attn dots) ------
// EPI: 0 = none, 1 = bias, 2 = bias+relu
// ATTN: 1 = also compute per-head attention dots from acc (requires NCOLS==256)

template <int K, int NCOLS, int EPI, int ATTN>
__global__ __launch_bounds__(256) void gemm_kernel(const float* __restrict__ A,
                                                   const float* __restrict__ B,
                                                   const float* __restrict__ bias,
                                                   float* __restrict__ C, int M,
                                                   const float* __restrict__ att_src,
                                                   const float* __restrict__ att_dst,
                                                   float* __restrict__ asrc_out,
                                                   float* __restrict__ adst_out) {
  constexpr int BM = 32, BK = 32;
  constexpr int CPT = NCOLS / 64;  // cols per thread
  __shared__ float As[BM][BK + 4];
  __shared__ float Bs[BK][NCOLS];
  int tid = threadIdx.x;
  int row0 = blockIdx.x * BM;
  int g = tid >> 6;       // wave id -> row group (8 rows each)
  int lane = tid & 63;
  int colBase = lane * CPT;

  float acc[8][CPT];
#pragma unroll
  for (int r = 0; r < 8; ++r)
#pragma unroll
    for (int j = 0; j < CPT; ++j) acc[r][j] = 0.f;

  for (int k0 = 0; k0 < K; k0 += BK) {
    // stage A tile (32x32), float4 per thread
    {
      int r = tid >> 3;
      int kc = (tid & 7) << 2;
      int grow = row0 + r;
      float4 av = make_float4(0.f, 0.f, 0.f, 0.f);
      if (grow < M) av = *(const float4*)(A + (size_t)grow * K + k0 + kc);
      *(float4*)&As[r][kc] = av;
    }
    // stage B tile (32 x NCOLS)
    {
      constexpr int PT = BK * NCOLS / 1024;  // float4s per thread
#pragma unroll
      for (int i = 0; i < PT; ++i) {
        int idx = (i * 256 + tid) * 4;
        int kk = idx / NCOLS;
        int cc = idx % NCOLS;
        *(float4*)&Bs[kk][cc] = *(const float4*)(B + (size_t)(k0 + kk) * NCOLS + cc);
      }
    }
    __syncthreads();
#pragma unroll
    for (int kk = 0; kk < BK; kk += 4) {
      float a4[8][4];
#pragma unroll
      for (int rr = 0; rr < 8; ++rr) {
        float4 t = *(const float4*)&As[g * 8 + rr][kk];
        a4[rr][0] = t.x; a4[rr][1] = t.y; a4[rr][2] = t.z; a4[rr][3] = t.w;
      }
      float b4[4][CPT];
#pragma unroll
      for (int u = 0; u < 4; ++u) {
        if constexpr (CPT == 4) {
          float4 t = *(const float4*)&Bs[kk + u][colBase];
          b4[u][0] = t.x; b4[u][1] = t.y; b4[u][2] = t.z; b4[u][3] = t.w;
        } else if constexpr (CPT == 2) {
          float2 t = *(const float2*)&Bs[kk + u][colBase];
          b4[u][0] = t.x; b4[u][1] = t.y;
        } else {
          b4[u][0] = Bs[kk + u][colBase];
        }
      }
#pragma unroll
      for (int u = 0; u < 4; ++u)
#pragma unroll
        for (int rr = 0; rr < 8; ++rr)
#pragma unroll
          for (int j = 0; j < CPT; ++j) acc[rr][j] += a4[rr][u] * b4[u][j];
    }
    __syncthreads();
  }

  if constexpr (ATTN) {
    // lane owns channels lane*4..lane*4+3, all within head lane>>4.
    // asrc[row*4+h] = sum over head-h channels of xl[row][c]*att_src[c]
    float4 s4 = *(const float4*)(att_src + lane * 4);
    float4 d4 = *(const float4*)(att_dst + lane * 4);
#pragma unroll
    for (int rr = 0; rr < 8; ++rr) {
      int row = row0 + g * 8 + rr;
      float ps = acc[rr][0] * s4.x + acc[rr][1] * s4.y + acc[rr][2] * s4.z + acc[rr][3] * s4.w;
      float pd = acc[rr][0] * d4.x + acc[rr][1] * d4.y + acc[rr][2] * d4.z + acc[rr][3] * d4.w;
#pragma unroll
      for (int m = 8; m >= 1; m >>= 1) {
        ps += __shfl_xor(ps, m);
        pd += __shfl_xor(pd, m);
      }
      if (row < M && (lane & 15) == 0) {
        asrc_out[row * 4 + (lane >> 4)] = ps;
        adst_out[row * 4 + (lane >> 4)] = pd;
      }
    }
  }

#pragma unroll
  for (int rr = 0; rr < 8; ++rr) {
    int row = row0 + g * 8 + rr;
    if (row >= M) continue;
#pragma unroll
    for (int j = 0; j < CPT; ++j) {
      float v = acc[rr][j];
      if constexpr (EPI >= 1) v += bias[colBase + j];
      if constexpr (EPI == 2) v = fmaxf(v, 0.f);
      C[(size_t)row * NCOLS + colBase + j] = v;
    }
  }
}

// ---------------- fused GAT aggregation + bias + ELU + residual + LayerNorm ----------------
// Lane l owns channels 4l..4l+3 (head h = l>>4). One wave per dst node.
// Chunk-4 edge pipeline: ssrc prefetched 2 chunks ahead, asrc/xl 1 chunk ahead.
// MODE 0: residual is h0 (64-dim); MODE 1: residual is full 256-dim

template <int MODE>
__global__ __launch_bounds__(256) void agg_kernel(
    const int* __restrict__ off, const int* __restrict__ ssrc,
    const float* __restrict__ asrc, const float* __restrict__ adst,
    const float* __restrict__ xl, const float* __restrict__ bias,
    const float* __restrict__ resid, const float* __restrict__ ln_g,
    const float* __restrict__ ln_b, float* __restrict__ hout) {
  int w = threadIdx.x >> 6, lane = threadIdx.x & 63;
  int n = blockIdx.x * 4 + w;
  if (n >= N_NODES) return;
  int h = lane >> 4;
  int ch = lane << 2;
  float ad = adst[n * 4 + h];

  int i0 = off[n], i1 = off[n + 1];
  int last = i1 - 1;

  float4 acc = make_float4(0.f, 0.f, 0.f, 0.f);
  float wsum = 0.f;

  // prologue: chunk 0 s-values, then a/x for chunk 0, then chunk 1 s-values
  int sA[4];
#pragma unroll
  for (int j = 0; j < 4; ++j) sA[j] = ssrc[min(i0 + j, last)];
  float ca[4]; float4 cx[4];
#pragma unroll
  for (int j = 0; j < 4; ++j) {
    ca[j] = asrc[sA[j] * 4 + h];
    cx[j] = *(const float4*)(xl + (size_t)sA[j] * HC + ch);
  }
#pragma unroll
  for (int j = 0; j < 4; ++j) sA[j] = ssrc[min(i0 + 4 + j, last)];

#pragma unroll 2
  for (int base = i0; base < i1; base += 4) {
    // issue a/x for next chunk (sA resident: issued one iteration ago)
    float na[4]; float4 nx[4];
#pragma unroll
    for (int j = 0; j < 4; ++j) {
      na[j] = asrc[sA[j] * 4 + h];
      nx[j] = *(const float4*)(xl + (size_t)sA[j] * HC + ch);
    }
    // issue ssrc for chunk k+2
#pragma unroll
    for (int j = 0; j < 4; ++j) sA[j] = ssrc[min(base + 8 + j, last)];
    // process current chunk
#pragma unroll
    for (int j = 0; j < 4; ++j) {
      float e = ca[j] + ad;
      e = e > 0.f ? e : 0.2f * e;
      float wg = __expf(e);
      wg = (base + j < i1) ? wg : 0.f;
      wsum += wg;
      acc.x = fmaf(wg, cx[j].x, acc.x);
      acc.y = fmaf(wg, cx[j].y, acc.y);
      acc.z = fmaf(wg, cx[j].z, acc.z);
      acc.w = fmaf(wg, cx[j].w, acc.w);
    }
    // rotate
#pragma unroll
    for (int j = 0; j < 4; ++j) { ca[j] = na[j]; cx[j] = nx[j]; }
  }

  float rw = 1.f / wsum;
  float4 b4 = *(const float4*)(bias + ch);
  float v0 = fmaf(acc.x, rw, b4.x);
  float v1 = fmaf(acc.y, rw, b4.y);
  float v2 = fmaf(acc.z, rw, b4.z);
  float v3 = fmaf(acc.w, rw, b4.w);
  v0 = v0 > 0.f ? v0 : __expf(v0) - 1.f;
  v1 = v1 > 0.f ? v1 : __expf(v1) - 1.f;
  v2 = v2 > 0.f ? v2 : __expf(v2) - 1.f;
  v3 = v3 > 0.f ? v3 : __expf(v3) - 1.f;

  if constexpr (MODE == 0) {
    if (lane < 16) {
      float4 r = *(const float4*)(resid + (size_t)n * 64 + ch);
      v0 += r.x; v1 += r.y; v2 += r.z; v3 += r.w;
    }
  } else {
    float4 r = *(const float4*)(resid + (size_t)n * HC + ch);
    v0 += r.x; v1 += r.y; v2 += r.z; v3 += r.w;
  }

  float s1 = v0 + v1 + v2 + v3;
  float s2 = v0 * v0 + v1 * v1 + v2 * v2 + v3 * v3;
#pragma unroll
  for (int m = 32; m >= 1; m >>= 1) {
    s1 += __shfl_xor(s1, m);
    s2 += __shfl_xor(s2, m);
  }
  float mean = s1 * (1.f / 256.f);
  float var = s2 * (1.f / 256.f) - mean * mean;
  float inv = rsqrtf(var + 1e-5f);

  float4 g4 = *(const float4*)(ln_g + ch);
  float4 lb4 = *(const float4*)(ln_b + ch);
  float4 o;
  o.x = (v0 - mean) * inv * g4.x + lb4.x;
  o.y = (v1 - mean) * inv * g4.y + lb4.y;
  o.z = (v2 - mean) * inv * g4.z + lb4.z;
  o.w = (v3 - mean) * inv * g4.w + lb4.w;
  *(float4*)(hout + (size_t)n * HC + ch) = o;
}

// ---------------- launch ----------------

extern "C" void kernel_launch(void* const* d_in, const int* in_sizes, int n_in,
                              void* d_out, int out_size, void* d_ws, size_t ws_size,
                              hipStream_t stream) {
  (void)in_sizes; (void)n_in; (void)out_size; (void)ws_size;
  const float* x      = (const float*)d_in[0];
  const int*   edges  = (const int*)d_in[1];
  const float* lin_w  = (const float*)d_in[2];
  const float* lin_b  = (const float*)d_in[3];
  const float* gat_w[3] = {(const float*)d_in[4], (const float*)d_in[10], (const float*)d_in[16]};
  const float* att_s[3] = {(const float*)d_in[5], (const float*)d_in[11], (const float*)d_in[17]};
  const float* att_d[3] = {(const float*)d_in[6], (const float*)d_in[12], (const float*)d_in[18]};
  const float* gat_b[3] = {(const float*)d_in[7], (const float*)d_in[13], (const float*)d_in[19]};
  const float* ln_g[3]  = {(const float*)d_in[8], (const float*)d_in[14], (const float*)d_in[20]};
  const float* ln_b[3]  = {(const float*)d_in[9], (const float*)d_in[15], (const float*)d_in[21]};
  const float* ffn_w1 = (const float*)d_in[22];
  const float* ffn_b1 = (const float*)d_in[23];
  const float* ffn_w2 = (const float*)d_in[24];
  const float* ffn_b2 = (const float*)d_in[25];

  char* p = (char*)d_ws;
  auto alloc = [&](size_t bytes) {
    char* q = p;
    p += (bytes + 255) & ~(size_t)255;
    return q;
  };
  int* off   = (int*)alloc((N_NODES + 1) * 4);
  int* cnt   = (int*)alloc(N_NODES * 4);
  int* cnt2  = (int*)alloc(N_NODES * 4);
  int* ssrc  = (int*)alloc((size_t)EL * 4);
  float* h0  = (float*)alloc((size_t)N_NODES * 64 * 4);
  float* hA  = (float*)alloc((size_t)N_NODES * HC * 4);
  float* hB  = (float*)alloc((size_t)N_NODES * HC * 4);
  float* xl  = (float*)alloc((size_t)N_NODES * HC * 4);
  float* as4 = (float*)alloc((size_t)N_NODES * 16);
  float* ad4 = (float*)alloc((size_t)N_NODES * 16);
  float* mid = xl;  // alias: xl dead by FFN time; mid needs N*128 <= N*256

  // CSR build (deterministic up to within-segment order; only affects fp sum order)
  zero_kernel<<<(N_NODES + 255) / 256, 256, 0, stream>>>(cnt, cnt2);
  hist_kernel<<<(EL + 255) / 256, 256, 0, stream>>>(edges, cnt);
  scan_kernel<<<1, 1024, 0, stream>>>(cnt, off);
  scatter_kernel<<<(EL + 255) / 256, 256, 0, stream>>>(edges, off, cnt2, ssrc);

  const int gblk = (N_NODES + 31) / 32;
  const int nblk = (N_NODES + 3) / 4;

  // h0 = relu(x @ lin_w + lin_b)
  gemm_kernel<64, 64, 2, 0><<<gblk, 256, 0, stream>>>(x, lin_w, lin_b, h0, N_NODES,
                                                      nullptr, nullptr, nullptr, nullptr);

  // layer 0 (in: h0 64-dim, residual pad); attn dots fused in GEMM epilogue
  gemm_kernel<64, 256, 0, 1><<<gblk, 256, 0, stream>>>(h0, gat_w[0], nullptr, xl, N_NODES,
                                                       att_s[0], att_d[0], as4, ad4);
  agg_kernel<0><<<nblk, 256, 0, stream>>>(off, ssrc, as4, ad4,
                                          xl, gat_b[0], h0, ln_g[0], ln_b[0], hA);
  // layer 1
  gemm_kernel<256, 256, 0, 1><<<gblk, 256, 0, stream>>>(hA, gat_w[1], nullptr, xl, N_NODES,
                                                        att_s[1], att_d[1], as4, ad4);
  agg_kernel<1><<<nblk, 256, 0, stream>>>(off, ssrc, as4, ad4,
                                          xl, gat_b[1], hA, ln_g[1], ln_b[1], hB);
  // layer 2
  gemm_kernel<256, 256, 0, 1><<<gblk, 256, 0, stream>>>(hB, gat_w[2], nullptr, xl, N_NODES,
                                                        att_s[2], att_d[2], as4, ad4);
  agg_kernel<1><<<nblk, 256, 0, stream>>>(off, ssrc, as4, ad4,
                                          xl, gat_b[2], hB, ln_g[2], ln_b[2], hA);

  // FFN: out = relu(hA @ w1 + b1) @ w2 + b2
  gemm_kernel<256, 128, 2, 0><<<gblk, 256, 0, stream>>>(hA, ffn_w1, ffn_b1, mid, N_NODES,
                                                        nullptr, nullptr, nullptr, nullptr);
  gemm_kernel<128, 64, 1, 0><<<gblk, 256, 0, stream>>>(mid, ffn_w2, ffn_b2, (float*)d_out, N_NODES,
                                                       nullptr, nullptr, nullptr, nullptr);
}

// Round 9
// 249.565 us; speedup vs baseline: 1.6646x; 1.2698x over previous
//
#include <hip/hip_runtime.h>

#define N_NODES 10000
#define N_EDGES 320000
#define EL (N_EDGES + N_NODES)
#define HC 256

__device__ __forceinline__ float bf2f(unsigned short u) {
  union { unsigned int i; float f; } v; v.i = ((unsigned int)u) << 16; return v.f;
}
__device__ __forceinline__ unsigned short f2bf(float f) {
  union { float f; unsigned int i; } v; v.f = f;
  unsigned int r = (v.i + 0x7FFFu + ((v.i >> 16) & 1u)) >> 16;
  return (unsigned short)r;
}

// ---------------- CSR build ----------------

__global__ void zero_kernel(int* __restrict__ cnt, int* __restrict__ cnt2) {
  int i = blockIdx.x * blockDim.x + threadIdx.x;
  if (i < N_NODES) { cnt[i] = 0; cnt2[i] = 0; }
}

__global__ void hist_kernel(const int* __restrict__ edges, int* __restrict__ cnt) {
  int e = blockIdx.x * blockDim.x + threadIdx.x;
  if (e >= EL) return;
  int d = (e < N_EDGES) ? edges[N_EDGES + e] : (e - N_EDGES);
  atomicAdd(&cnt[d], 1);
}

__global__ void scan_kernel(const int* __restrict__ cnt, int* __restrict__ off) {
  __shared__ int sums[1024];
  const int CH = 10;
  int t = threadIdx.x;
  int base = t * CH;
  int local[CH];
  int run = 0;
#pragma unroll
  for (int i = 0; i < CH; ++i) {
    int idx = base + i;
    int v = (idx < N_NODES) ? cnt[idx] : 0;
    local[i] = run;
    run += v;
  }
  sums[t] = run;
  __syncthreads();
  for (int d = 1; d < 1024; d <<= 1) {
    int v = (t >= d) ? sums[t - d] : 0;
    __syncthreads();
    sums[t] += v;
    __syncthreads();
  }
  int pre = (t > 0) ? sums[t - 1] : 0;
#pragma unroll
  for (int i = 0; i < CH; ++i) {
    int idx = base + i;
    if (idx < N_NODES) off[idx] = pre + local[i];
  }
  if (t == 1023) off[N_NODES] = sums[1023];
}

__global__ void scatter_kernel(const int* __restrict__ edges, const int* __restrict__ off,
                               int* __restrict__ tmp, int* __restrict__ ssrc) {
  int e = blockIdx.x * blockDim.x + threadIdx.x;
  if (e >= EL) return;
  int s, d;
  if (e < N_EDGES) { s = edges[e]; d = edges[N_EDGES + e]; }
  else { s = d = e - N_EDGES; }
  int pos = off[d] + atomicAdd(&tmp[d], 1);
  ssrc[pos] = s;
}

// ---------------- GEMM: BM=16 rows/block (625 blocks, M=10000 exact) ----------------
// EPI: 0 none, 1 bias, 2 bias+relu.  ATTN: fused per-head attention dots (NCOLS==256).
// OBF: write output as bf16 to Cb instead of f32 to C (NCOLS==256, CPT==4).

template <int K, int NCOLS, int EPI, int ATTN, int OBF>
__global__ __launch_bounds__(256) void gemm_kernel(const float* __restrict__ A,
                                                   const float* __restrict__ B,
                                                   const float* __restrict__ bias,
                                                   float* __restrict__ C,
                                                   unsigned short* __restrict__ Cb,
                                                   const float* __restrict__ att_src,
                                                   const float* __restrict__ att_dst,
                                                   float* __restrict__ asrc_out,
                                                   float* __restrict__ adst_out) {
  constexpr int BM = 16, BK = 32;
  constexpr int CPT = NCOLS / 64;
  __shared__ float As[BM][BK + 4];
  __shared__ float Bs[BK][NCOLS];
  int tid = threadIdx.x;
  int row0 = blockIdx.x * BM;
  int g = tid >> 6;      // wave -> 4 rows
  int lane = tid & 63;
  int colBase = lane * CPT;

  float acc[4][CPT];
#pragma unroll
  for (int r = 0; r < 4; ++r)
#pragma unroll
    for (int j = 0; j < CPT; ++j) acc[r][j] = 0.f;

  for (int k0 = 0; k0 < K; k0 += BK) {
    if (tid < 128) {  // stage A tile 16x32
      int r = tid >> 3;
      int kc = (tid & 7) << 2;
      *(float4*)&As[r][kc] = *(const float4*)(A + (size_t)(row0 + r) * K + k0 + kc);
    }
    {  // stage B tile 32 x NCOLS
      constexpr int PT = BK * NCOLS / 1024;
#pragma unroll
      for (int i = 0; i < PT; ++i) {
        int idx = (i * 256 + tid) * 4;
        int kk = idx / NCOLS;
        int cc = idx % NCOLS;
        *(float4*)&Bs[kk][cc] = *(const float4*)(B + (size_t)(k0 + kk) * NCOLS + cc);
      }
    }
    __syncthreads();
#pragma unroll
    for (int kk = 0; kk < BK; kk += 4) {
      float a4[4][4];
#pragma unroll
      for (int rr = 0; rr < 4; ++rr) {
        float4 t = *(const float4*)&As[g * 4 + rr][kk];
        a4[rr][0] = t.x; a4[rr][1] = t.y; a4[rr][2] = t.z; a4[rr][3] = t.w;
      }
      float b4[4][CPT];
#pragma unroll
      for (int u = 0; u < 4; ++u) {
        if constexpr (CPT == 4) {
          float4 t = *(const float4*)&Bs[kk + u][colBase];
          b4[u][0] = t.x; b4[u][1] = t.y; b4[u][2] = t.z; b4[u][3] = t.w;
        } else if constexpr (CPT == 2) {
          float2 t = *(const float2*)&Bs[kk + u][colBase];
          b4[u][0] = t.x; b4[u][1] = t.y;
        } else {
          b4[u][0] = Bs[kk + u][colBase];
        }
      }
#pragma unroll
      for (int u = 0; u < 4; ++u)
#pragma unroll
        for (int rr = 0; rr < 4; ++rr)
#pragma unroll
          for (int j = 0; j < CPT; ++j) acc[rr][j] += a4[rr][u] * b4[u][j];
    }
    __syncthreads();
  }

  if constexpr (ATTN) {
    float4 s4 = *(const float4*)(att_src + lane * 4);
    float4 d4 = *(const float4*)(att_dst + lane * 4);
#pragma unroll
    for (int rr = 0; rr < 4; ++rr) {
      int row = row0 + g * 4 + rr;
      float ps = acc[rr][0] * s4.x + acc[rr][1] * s4.y + acc[rr][2] * s4.z + acc[rr][3] * s4.w;
      float pd = acc[rr][0] * d4.x + acc[rr][1] * d4.y + acc[rr][2] * d4.z + acc[rr][3] * d4.w;
#pragma unroll
      for (int m = 8; m >= 1; m >>= 1) {
        ps += __shfl_xor(ps, m);
        pd += __shfl_xor(pd, m);
      }
      if ((lane & 15) == 0) {
        asrc_out[row * 4 + (lane >> 4)] = ps;
        adst_out[row * 4 + (lane >> 4)] = pd;
      }
    }
  }

#pragma unroll
  for (int rr = 0; rr < 4; ++rr) {
    int row = row0 + g * 4 + rr;
    if constexpr (OBF) {
      ushort4 o;
      o.x = f2bf(acc[rr][0]); o.y = f2bf(acc[rr][1]);
      o.z = f2bf(acc[rr][2]); o.w = f2bf(acc[rr][3]);
      *(ushort4*)(Cb + (size_t)row * NCOLS + colBase) = o;
    } else {
#pragma unroll
      for (int j = 0; j < CPT; ++j) {
        float v = acc[rr][j];
        if constexpr (EPI >= 1) v += bias[colBase + j];
        if constexpr (EPI == 2) v = fmaxf(v, 0.f);
        C[(size_t)row * NCOLS + colBase + j] = v;
      }
    }
  }
}

// ---------------- fused GAT aggregation + bias + ELU + residual + LayerNorm ----------------
// Lane l owns channels 4l..4l+3 (head h = l>>4). One wave per dst node.
// Gathered features in bf16 (halved traffic); coeffs + accumulation in f32.
// Chunk-4 pipeline: ssrc 2 chunks ahead, asrc/xb 1 chunk ahead.

template <int MODE>
__global__ __launch_bounds__(256) void agg_kernel(
    const int* __restrict__ off, const int* __restrict__ ssrc,
    const float* __restrict__ asrc, const float* __restrict__ adst,
    const unsigned short* __restrict__ xb, const float* __restrict__ bias,
    const float* __restrict__ resid, const float* __restrict__ ln_g,
    const float* __restrict__ ln_b, float* __restrict__ hout) {
  int w = threadIdx.x >> 6, lane = threadIdx.x & 63;
  int n = blockIdx.x * 4 + w;
  int h = lane >> 4;
  int ch = lane << 2;
  float ad = adst[n * 4 + h];

  int i0 = off[n], i1 = off[n + 1];
  int last = i1 - 1;

  float4 acc = make_float4(0.f, 0.f, 0.f, 0.f);
  float wsum = 0.f;

  int sA[4];
#pragma unroll
  for (int j = 0; j < 4; ++j) sA[j] = ssrc[min(i0 + j, last)];
  float ca[4]; ushort4 cx[4];
#pragma unroll
  for (int j = 0; j < 4; ++j) {
    ca[j] = asrc[sA[j] * 4 + h];
    cx[j] = *(const ushort4*)(xb + (size_t)sA[j] * HC + ch);
  }
#pragma unroll
  for (int j = 0; j < 4; ++j) sA[j] = ssrc[min(i0 + 4 + j, last)];

#pragma unroll 2
  for (int base = i0; base < i1; base += 4) {
    float na[4]; ushort4 nx[4];
#pragma unroll
    for (int j = 0; j < 4; ++j) {
      na[j] = asrc[sA[j] * 4 + h];
      nx[j] = *(const ushort4*)(xb + (size_t)sA[j] * HC + ch);
    }
#pragma unroll
    for (int j = 0; j < 4; ++j) sA[j] = ssrc[min(base + 8 + j, last)];
#pragma unroll
    for (int j = 0; j < 4; ++j) {
      float e = ca[j] + ad;
      e = e > 0.f ? e : 0.2f * e;
      float wg = __expf(e);
      wg = (base + j < i1) ? wg : 0.f;
      wsum += wg;
      acc.x = fmaf(wg, bf2f(cx[j].x), acc.x);
      acc.y = fmaf(wg, bf2f(cx[j].y), acc.y);
      acc.z = fmaf(wg, bf2f(cx[j].z), acc.z);
      acc.w = fmaf(wg, bf2f(cx[j].w), acc.w);
    }
#pragma unroll
    for (int j = 0; j < 4; ++j) { ca[j] = na[j]; cx[j] = nx[j]; }
  }

  float rw = 1.f / wsum;
  float4 b4 = *(const float4*)(bias + ch);
  float v0 = fmaf(acc.x, rw, b4.x);
  float v1 = fmaf(acc.y, rw, b4.y);
  float v2 = fmaf(acc.z, rw, b4.z);
  float v3 = fmaf(acc.w, rw, b4.w);
  v0 = v0 > 0.f ? v0 : __expf(v0) - 1.f;
  v1 = v1 > 0.f ? v1 : __expf(v1) - 1.f;
  v2 = v2 > 0.f ? v2 : __expf(v2) - 1.f;
  v3 = v3 > 0.f ? v3 : __expf(v3) - 1.f;

  if constexpr (MODE == 0) {
    if (lane < 16) {
      float4 r = *(const float4*)(resid + (size_t)n * 64 + ch);
      v0 += r.x; v1 += r.y; v2 += r.z; v3 += r.w;
    }
  } else {
    float4 r = *(const float4*)(resid + (size_t)n * HC + ch);
    v0 += r.x; v1 += r.y; v2 += r.z; v3 += r.w;
  }

  float s1 = v0 + v1 + v2 + v3;
  float s2 = v0 * v0 + v1 * v1 + v2 * v2 + v3 * v3;
#pragma unroll
  for (int m = 32; m >= 1; m >>= 1) {
    s1 += __shfl_xor(s1, m);
    s2 += __shfl_xor(s2, m);
  }
  float mean = s1 * (1.f / 256.f);
  float var = s2 * (1.f / 256.f) - mean * mean;
  float inv = rsqrtf(var + 1e-5f);

  float4 g4 = *(const float4*)(ln_g + ch);
  float4 lb4 = *(const float4*)(ln_b + ch);
  float4 o;
  o.x = (v0 - mean) * inv * g4.x + lb4.x;
  o.y = (v1 - mean) * inv * g4.y + lb4.y;
  o.z = (v2 - mean) * inv * g4.z + lb4.z;
  o.w = (v3 - mean) * inv * g4.w + lb4.w;
  *(float4*)(hout + (size_t)n * HC + ch) = o;
}

// ---------------- launch ----------------

extern "C" void kernel_launch(void* const* d_in, const int* in_sizes, int n_in,
                              void* d_out, int out_size, void* d_ws, size_t ws_size,
                              hipStream_t stream) {
  (void)in_sizes; (void)n_in; (void)out_size; (void)ws_size;
  const float* x      = (const float*)d_in[0];
  const int*   edges  = (const int*)d_in[1];
  const float* lin_w  = (const float*)d_in[2];
  const float* lin_b  = (const float*)d_in[3];
  const float* gat_w[3] = {(const float*)d_in[4], (const float*)d_in[10], (const float*)d_in[16]};
  const float* att_s[3] = {(const float*)d_in[5], (const float*)d_in[11], (const float*)d_in[17]};
  const float* att_d[3] = {(const float*)d_in[6], (const float*)d_in[12], (const float*)d_in[18]};
  const float* gat_b[3] = {(const float*)d_in[7], (const float*)d_in[13], (const float*)d_in[19]};
  const float* ln_g[3]  = {(const float*)d_in[8], (const float*)d_in[14], (const float*)d_in[20]};
  const float* ln_b[3]  = {(const float*)d_in[9], (const float*)d_in[15], (const float*)d_in[21]};
  const float* ffn_w1 = (const float*)d_in[22];
  const float* ffn_b1 = (const float*)d_in[23];
  const float* ffn_w2 = (const float*)d_in[24];
  const float* ffn_b2 = (const float*)d_in[25];

  char* p = (char*)d_ws;
  auto alloc = [&](size_t bytes) {
    char* q = p;
    p += (bytes + 255) & ~(size_t)255;
    return q;
  };
  int* off   = (int*)alloc((N_NODES + 1) * 4);
  int* cnt   = (int*)alloc(N_NODES * 4);
  int* cnt2  = (int*)alloc(N_NODES * 4);
  int* ssrc  = (int*)alloc((size_t)EL * 4);
  float* h0  = (float*)alloc((size_t)N_NODES * 64 * 4);
  float* hA  = (float*)alloc((size_t)N_NODES * HC * 4);
  float* hB  = (float*)alloc((size_t)N_NODES * HC * 4);
  unsigned short* xb = (unsigned short*)alloc((size_t)N_NODES * HC * 2);
  float* as4 = (float*)alloc((size_t)N_NODES * 16);
  float* ad4 = (float*)alloc((size_t)N_NODES * 16);
  float* mid = hB;  // hB dead after layer-2 agg; mid needs N*128 <= N*256

  zero_kernel<<<(N_NODES + 255) / 256, 256, 0, stream>>>(cnt, cnt2);
  hist_kernel<<<(EL + 255) / 256, 256, 0, stream>>>(edges, cnt);
  scan_kernel<<<1, 1024, 0, stream>>>(cnt, off);
  scatter_kernel<<<(EL + 255) / 256, 256, 0, stream>>>(edges, off, cnt2, ssrc);

  const int gblk = N_NODES / 16;      // 625
  const int nblk = N_NODES / 4;       // 2500

  // h0 = relu(x @ lin_w + lin_b)
  gemm_kernel<64, 64, 2, 0, 0><<<gblk, 256, 0, stream>>>(x, lin_w, lin_b, h0, nullptr,
                                                         nullptr, nullptr, nullptr, nullptr);

  // layer 0: xl (bf16) + fused attn dots
  gemm_kernel<64, 256, 0, 1, 1><<<gblk, 256, 0, stream>>>(h0, gat_w[0], nullptr, nullptr, xb,
                                                          att_s[0], att_d[0], as4, ad4);
  agg_kernel<0><<<nblk, 256, 0, stream>>>(off, ssrc, as4, ad4, xb, gat_b[0], h0,
                                          ln_g[0], ln_b[0], hA);
  // layer 1
  gemm_kernel<256, 256, 0, 1, 1><<<gblk, 256, 0, stream>>>(hA, gat_w[1], nullptr, nullptr, xb,
                                                           att_s[1], att_d[1], as4, ad4);
  agg_kernel<1><<<nblk, 256, 0, stream>>>(off, ssrc, as4, ad4, xb, gat_b[1], hA,
                                          ln_g[1], ln_b[1], hB);
  // layer 2
  gemm_kernel<256, 256, 0, 1, 1><<<gblk, 256, 0, stream>>>(hB, gat_w[2], nullptr, nullptr, xb,
                                                           att_s[2], att_d[2], as4, ad4);
  agg_kernel<1><<<nblk, 256, 0, stream>>>(off, ssrc, as4, ad4, xb, gat_b[2], hB,
                                          ln_g[2], ln_b[2], hA);

  // FFN: out = relu(hA @ w1 + b1) @ w2 + b2
  gemm_kernel<256, 128, 2, 0, 0><<<gblk, 256, 0, stream>>>(hA, ffn_w1, ffn_b1, mid, nullptr,
                                                           nullptr, nullptr, nullptr, nullptr);
  gemm_kernel<128, 64, 1, 0, 0><<<gblk, 256, 0, stream>>>(mid, ffn_w2, ffn_b2, (float*)d_out, nullptr,
                                                          nullptr, nullptr, nullptr, nullptr);
}

// Round 10
// 209.984 us; speedup vs baseline: 1.9784x; 1.1885x over previous
//
#include <hip/hip_runtime.h>

#define N_NODES 10000
#define N_EDGES 320000
#define EL (N_EDGES + N_NODES)
#define HC 256

using bf16x8 = __attribute__((ext_vector_type(8))) short;
using f32x4  = __attribute__((ext_vector_type(4))) float;

__device__ __forceinline__ float bf2f(unsigned short u) {
  union { unsigned int i; float f; } v; v.i = ((unsigned int)u) << 16; return v.f;
}
__device__ __forceinline__ unsigned short f2bf(float f) {
  union { float f; unsigned int i; } v; v.f = f;
  unsigned int r = (v.i + 0x7FFFu + ((v.i >> 16) & 1u)) >> 16;
  return (unsigned short)r;
}

// ---------------- CSR build ----------------

__global__ void zero_kernel(int* __restrict__ cnt, int* __restrict__ cnt2) {
  int i = blockIdx.x * blockDim.x + threadIdx.x;
  if (i < N_NODES) { cnt[i] = 0; cnt2[i] = 0; }
}

__global__ void hist_kernel(const int* __restrict__ edges, int* __restrict__ cnt) {
  int e = blockIdx.x * blockDim.x + threadIdx.x;
  if (e >= EL) return;
  int d = (e < N_EDGES) ? edges[N_EDGES + e] : (e - N_EDGES);
  atomicAdd(&cnt[d], 1);
}

__global__ void scan_kernel(const int* __restrict__ cnt, int* __restrict__ off) {
  __shared__ int sums[1024];
  const int CH = 10;
  int t = threadIdx.x;
  int base = t * CH;
  int local[CH];
  int run = 0;
#pragma unroll
  for (int i = 0; i < CH; ++i) {
    int idx = base + i;
    int v = (idx < N_NODES) ? cnt[idx] : 0;
    local[i] = run;
    run += v;
  }
  sums[t] = run;
  __syncthreads();
  for (int d = 1; d < 1024; d <<= 1) {
    int v = (t >= d) ? sums[t - d] : 0;
    __syncthreads();
    sums[t] += v;
    __syncthreads();
  }
  int pre = (t > 0) ? sums[t - 1] : 0;
#pragma unroll
  for (int i = 0; i < CH; ++i) {
    int idx = base + i;
    if (idx < N_NODES) off[idx] = pre + local[i];
  }
  if (t == 1023) off[N_NODES] = sums[1023];
}

__global__ void scatter_kernel(const int* __restrict__ edges, const int* __restrict__ off,
                               int* __restrict__ tmp, int* __restrict__ ssrc) {
  int e = blockIdx.x * blockDim.x + threadIdx.x;
  if (e >= EL) return;
  int s, d;
  if (e < N_EDGES) { s = edges[e]; d = edges[N_EDGES + e]; }
  else { s = d = e - N_EDGES; }
  int pos = off[d] + atomicAdd(&tmp[d], 1);
  ssrc[pos] = s;
}

// ---------------- weight transpose+convert: w [K][256] f32 -> bt [256][K] bf16 ----------

__global__ void convw_kernel(const float* __restrict__ w, unsigned short* __restrict__ bt, int K) {
  int idx = blockIdx.x * blockDim.x + threadIdx.x;
  int half = K >> 1;
  if (idx >= 256 * half) return;
  int col = idx / half;
  int k2 = (idx % half) * 2;
  ushort2 o;
  o.x = f2bf(w[(size_t)k2 * 256 + col]);
  o.y = f2bf(w[(size_t)(k2 + 1) * 256 + col]);
  *(ushort2*)(bt + (size_t)col * K + k2) = o;
}

// ---------------- MFMA GEMM (attn layers): Cb[M][256] bf16 = A[M][K] @ W, + attn dots ----
// Block: 16 rows x 256 cols, 4 waves; wave = head; wave handles col-tiles wave*4..+3.
// A staged f32->bf16 into LDS; Bt ([col][K] bf16) staged per 64-k slice. XOR swizzle
// (byte ^= (row&7)<<4) breaks the 128B-row 16-way bank conflict (G4).
// Frag layout (m89 convention): A row=lane&15,k=(lane>>4)*8+j; B col=lane&15;
// C/D col=lane&15, row=(lane>>4)*4+reg.

template <int K>
__global__ __launch_bounds__(256) void gemm_attn_mfma(
    const float* __restrict__ A, const unsigned short* __restrict__ Bt,
    unsigned short* __restrict__ Cb,
    const float* __restrict__ att_src, const float* __restrict__ att_dst,
    float* __restrict__ asrc_out, float* __restrict__ adst_out) {
  __shared__ __align__(16) unsigned short Asw[16 * 64];
  __shared__ __align__(16) unsigned short Bsw[256 * 64];
  int tid = threadIdx.x;
  int wave = tid >> 6, lane = tid & 63;
  int r = lane & 15, g = lane >> 4;
  int row0 = blockIdx.x * 16;

  f32x4 acc[4];
#pragma unroll
  for (int i = 0; i < 4; ++i) acc[i] = {0.f, 0.f, 0.f, 0.f};

  for (int k0 = 0; k0 < K; k0 += 64) {
    {  // stage A: 16 rows x 64 k, f32 -> bf16
      int ar = tid >> 4;
      int kc = (tid & 15) << 2;
      float4 av = *(const float4*)(A + (size_t)(row0 + ar) * K + k0 + kc);
      ushort4 o;
      o.x = f2bf(av.x); o.y = f2bf(av.y); o.z = f2bf(av.z); o.w = f2bf(av.w);
      *(ushort4*)((char*)Asw + ((ar * 128 + kc * 2) ^ ((ar & 7) << 4))) = o;
    }
#pragma unroll
    for (int i = 0; i < 8; ++i) {  // stage B: 256 cols x 64 k bf16 (32KB)
      int idx = i * 256 + tid;
      int col = idx >> 3;
      int kc8 = idx & 7;
      uint4 v = *(const uint4*)(Bt + (size_t)col * K + k0 + kc8 * 8);
      *(uint4*)((char*)Bsw + ((col * 128 + kc8 * 16) ^ ((col & 7) << 4))) = v;
    }
    __syncthreads();
#pragma unroll
    for (int chunk = 0; chunk < 2; ++chunk) {
      bf16x8 af = *(const bf16x8*)((char*)Asw +
                    ((r * 128 + chunk * 64 + g * 16) ^ ((r & 7) << 4)));
#pragma unroll
      for (int i = 0; i < 4; ++i) {
        int col = (wave * 4 + i) * 16 + r;
        bf16x8 bfr = *(const bf16x8*)((char*)Bsw +
                       ((col * 128 + chunk * 64 + g * 16) ^ ((col & 7) << 4)));
        acc[i] = __builtin_amdgcn_mfma_f32_16x16x32_bf16(af, bfr, acc[i], 0, 0, 0);
      }
    }
    __syncthreads();
  }

  // fused attention dots: wave == head; reduce across cols (lane&15 + the 4 col-tiles)
  float asv[4], adv[4];
#pragma unroll
  for (int i = 0; i < 4; ++i) {
    int col = (wave * 4 + i) * 16 + r;
    asv[i] = att_src[col];
    adv[i] = att_dst[col];
  }
#pragma unroll
  for (int j = 0; j < 4; ++j) {
    float ps = acc[0][j] * asv[0] + acc[1][j] * asv[1] + acc[2][j] * asv[2] + acc[3][j] * asv[3];
    float pd = acc[0][j] * adv[0] + acc[1][j] * adv[1] + acc[2][j] * adv[2] + acc[3][j] * adv[3];
#pragma unroll
    for (int m = 8; m >= 1; m >>= 1) {
      ps += __shfl_xor(ps, m);
      pd += __shfl_xor(pd, m);
    }
    if (r == 0) {
      int row = row0 + g * 4 + j;
      asrc_out[row * 4 + wave] = ps;
      adst_out[row * 4 + wave] = pd;
    }
  }

  // write xl as bf16
#pragma unroll
  for (int i = 0; i < 4; ++i) {
    int col = (wave * 4 + i) * 16 + r;
#pragma unroll
    for (int j = 0; j < 4; ++j) {
      int row = row0 + g * 4 + j;
      Cb[(size_t)row * 256 + col] = f2bf(acc[i][j]);
    }
  }
}

// ---------------- f32 GEMM (lin / ffn): BM=16 rows/block ----------------
// EPI: 0 none, 1 bias, 2 bias+relu

template <int K, int NCOLS, int EPI>
__global__ __launch_bounds__(256) void gemm_kernel(const float* __restrict__ A,
                                                   const float* __restrict__ B,
                                                   const float* __restrict__ bias,
                                                   float* __restrict__ C) {
  constexpr int BM = 16, BK = 32;
  constexpr int CPT = NCOLS / 64;
  __shared__ float As[BM][BK + 4];
  __shared__ float Bs[BK][NCOLS];
  int tid = threadIdx.x;
  int row0 = blockIdx.x * BM;
  int g = tid >> 6;
  int lane = tid & 63;
  int colBase = lane * CPT;

  float acc[4][CPT];
#pragma unroll
  for (int r = 0; r < 4; ++r)
#pragma unroll
    for (int j = 0; j < CPT; ++j) acc[r][j] = 0.f;

  for (int k0 = 0; k0 < K; k0 += BK) {
    if (tid < 128) {
      int r = tid >> 3;
      int kc = (tid & 7) << 2;
      *(float4*)&As[r][kc] = *(const float4*)(A + (size_t)(row0 + r) * K + k0 + kc);
    }
    {
      constexpr int PT = BK * NCOLS / 1024;
#pragma unroll
      for (int i = 0; i < PT; ++i) {
        int idx = (i * 256 + tid) * 4;
        int kk = idx / NCOLS;
        int cc = idx % NCOLS;
        *(float4*)&Bs[kk][cc] = *(const float4*)(B + (size_t)(k0 + kk) * NCOLS + cc);
      }
    }
    __syncthreads();
#pragma unroll
    for (int kk = 0; kk < BK; kk += 4) {
      float a4[4][4];
#pragma unroll
      for (int rr = 0; rr < 4; ++rr) {
        float4 t = *(const float4*)&As[g * 4 + rr][kk];
        a4[rr][0] = t.x; a4[rr][1] = t.y; a4[rr][2] = t.z; a4[rr][3] = t.w;
      }
      float b4[4][CPT];
#pragma unroll
      for (int u = 0; u < 4; ++u) {
        if constexpr (CPT == 4) {
          float4 t = *(const float4*)&Bs[kk + u][colBase];
          b4[u][0] = t.x; b4[u][1] = t.y; b4[u][2] = t.z; b4[u][3] = t.w;
        } else if constexpr (CPT == 2) {
          float2 t = *(const float2*)&Bs[kk + u][colBase];
          b4[u][0] = t.x; b4[u][1] = t.y;
        } else {
          b4[u][0] = Bs[kk + u][colBase];
        }
      }
#pragma unroll
      for (int u = 0; u < 4; ++u)
#pragma unroll
        for (int rr = 0; rr < 4; ++rr)
#pragma unroll
          for (int j = 0; j < CPT; ++j) acc[rr][j] += a4[rr][u] * b4[u][j];
    }
    __syncthreads();
  }

#pragma unroll
  for (int rr = 0; rr < 4; ++rr) {
    int row = row0 + g * 4 + rr;
#pragma unroll
    for (int j = 0; j < CPT; ++j) {
      float v = acc[rr][j];
      if constexpr (EPI >= 1) v += bias[colBase + j];
      if constexpr (EPI == 2) v = fmaxf(v, 0.f);
      C[(size_t)row * NCOLS + colBase + j] = v;
    }
  }
}

// ---------------- fused GAT aggregation + bias + ELU + residual + LayerNorm ----------------

template <int MODE>
__global__ __launch_bounds__(256) void agg_kernel(
    const int* __restrict__ off, const int* __restrict__ ssrc,
    const float* __restrict__ asrc, const float* __restrict__ adst,
    const unsigned short* __restrict__ xb, const float* __restrict__ bias,
    const float* __restrict__ resid, const float* __restrict__ ln_g,
    const float* __restrict__ ln_b, float* __restrict__ hout) {
  int w = threadIdx.x >> 6, lane = threadIdx.x & 63;
  int n = blockIdx.x * 4 + w;
  int h = lane >> 4;
  int ch = lane << 2;
  float ad = adst[n * 4 + h];

  int i0 = off[n], i1 = off[n + 1];
  int last = i1 - 1;

  float4 acc = make_float4(0.f, 0.f, 0.f, 0.f);
  float wsum = 0.f;

  int sA[4];
#pragma unroll
  for (int j = 0; j < 4; ++j) sA[j] = ssrc[min(i0 + j, last)];
  float ca[4]; ushort4 cx[4];
#pragma unroll
  for (int j = 0; j < 4; ++j) {
    ca[j] = asrc[sA[j] * 4 + h];
    cx[j] = *(const ushort4*)(xb + (size_t)sA[j] * HC + ch);
  }
#pragma unroll
  for (int j = 0; j < 4; ++j) sA[j] = ssrc[min(i0 + 4 + j, last)];

#pragma unroll 2
  for (int base = i0; base < i1; base += 4) {
    float na[4]; ushort4 nx[4];
#pragma unroll
    for (int j = 0; j < 4; ++j) {
      na[j] = asrc[sA[j] * 4 + h];
      nx[j] = *(const ushort4*)(xb + (size_t)sA[j] * HC + ch);
    }
#pragma unroll
    for (int j = 0; j < 4; ++j) sA[j] = ssrc[min(base + 8 + j, last)];
#pragma unroll
    for (int j = 0; j < 4; ++j) {
      float e = ca[j] + ad;
      e = e > 0.f ? e : 0.2f * e;
      float wg = __expf(e);
      wg = (base + j < i1) ? wg : 0.f;
      wsum += wg;
      acc.x = fmaf(wg, bf2f(cx[j].x), acc.x);
      acc.y = fmaf(wg, bf2f(cx[j].y), acc.y);
      acc.z = fmaf(wg, bf2f(cx[j].z), acc.z);
      acc.w = fmaf(wg, bf2f(cx[j].w), acc.w);
    }
#pragma unroll
    for (int j = 0; j < 4; ++j) { ca[j] = na[j]; cx[j] = nx[j]; }
  }

  float rw = 1.f / wsum;
  float4 b4 = *(const float4*)(bias + ch);
  float v0 = fmaf(acc.x, rw, b4.x);
  float v1 = fmaf(acc.y, rw, b4.y);
  float v2 = fmaf(acc.z, rw, b4.z);
  float v3 = fmaf(acc.w, rw, b4.w);
  v0 = v0 > 0.f ? v0 : __expf(v0) - 1.f;
  v1 = v1 > 0.f ? v1 : __expf(v1) - 1.f;
  v2 = v2 > 0.f ? v2 : __expf(v2) - 1.f;
  v3 = v3 > 0.f ? v3 : __expf(v3) - 1.f;

  if constexpr (MODE == 0) {
    if (lane < 16) {
      float4 r = *(const float4*)(resid + (size_t)n * 64 + ch);
      v0 += r.x; v1 += r.y; v2 += r.z; v3 += r.w;
    }
  } else {
    float4 r = *(const float4*)(resid + (size_t)n * HC + ch);
    v0 += r.x; v1 += r.y; v2 += r.z; v3 += r.w;
  }

  float s1 = v0 + v1 + v2 + v3;
  float s2 = v0 * v0 + v1 * v1 + v2 * v2 + v3 * v3;
#pragma unroll
  for (int m = 32; m >= 1; m >>= 1) {
    s1 += __shfl_xor(s1, m);
    s2 += __shfl_xor(s2, m);
  }
  float mean = s1 * (1.f / 256.f);
  float var = s2 * (1.f / 256.f) - mean * mean;
  float inv = rsqrtf(var + 1e-5f);

  float4 g4 = *(const float4*)(ln_g + ch);
  float4 lb4 = *(const float4*)(ln_b + ch);
  float4 o;
  o.x = (v0 - mean) * inv * g4.x + lb4.x;
  o.y = (v1 - mean) * inv * g4.y + lb4.y;
  o.z = (v2 - mean) * inv * g4.z + lb4.z;
  o.w = (v3 - mean) * inv * g4.w + lb4.w;
  *(float4*)(hout + (size_t)n * HC + ch) = o;
}

// ---------------- launch ----------------

extern "C" void kernel_launch(void* const* d_in, const int* in_sizes, int n_in,
                              void* d_out, int out_size, void* d_ws, size_t ws_size,
                              hipStream_t stream) {
  (void)in_sizes; (void)n_in; (void)out_size; (void)ws_size;
  const float* x      = (const float*)d_in[0];
  const int*   edges  = (const int*)d_in[1];
  const float* lin_w  = (const float*)d_in[2];
  const float* lin_b  = (const float*)d_in[3];
  const float* gat_w[3] = {(const float*)d_in[4], (const float*)d_in[10], (const float*)d_in[16]};
  const float* att_s[3] = {(const float*)d_in[5], (const float*)d_in[11], (const float*)d_in[17]};
  const float* att_d[3] = {(const float*)d_in[6], (const float*)d_in[12], (const float*)d_in[18]};
  const float* gat_b[3] = {(const float*)d_in[7], (const float*)d_in[13], (const float*)d_in[19]};
  const float* ln_g[3]  = {(const float*)d_in[8], (const float*)d_in[14], (const float*)d_in[20]};
  const float* ln_b[3]  = {(const float*)d_in[9], (const float*)d_in[15], (const float*)d_in[21]};
  const float* ffn_w1 = (const float*)d_in[22];
  const float* ffn_b1 = (const float*)d_in[23];
  const float* ffn_w2 = (const float*)d_in[24];
  const float* ffn_b2 = (const float*)d_in[25];

  char* p = (char*)d_ws;
  auto alloc = [&](size_t bytes) {
    char* q = p;
    p += (bytes + 255) & ~(size_t)255;
    return q;
  };
  int* off   = (int*)alloc((N_NODES + 1) * 4);
  int* cnt   = (int*)alloc(N_NODES * 4);
  int* cnt2  = (int*)alloc(N_NODES * 4);
  int* ssrc  = (int*)alloc((size_t)EL * 4);
  float* h0  = (float*)alloc((size_t)N_NODES * 64 * 4);
  float* hA  = (float*)alloc((size_t)N_NODES * HC * 4);
  float* hB  = (float*)alloc((size_t)N_NODES * HC * 4);
  unsigned short* xb = (unsigned short*)alloc((size_t)N_NODES * HC * 2);
  float* as4 = (float*)alloc((size_t)N_NODES * 16);
  float* ad4 = (float*)alloc((size_t)N_NODES * 16);
  unsigned short* bt0 = (unsigned short*)alloc(256 * 64 * 2);
  unsigned short* bt1 = (unsigned short*)alloc(256 * 256 * 2);
  unsigned short* bt2 = (unsigned short*)alloc(256 * 256 * 2);
  float* mid = hB;  // hB dead after layer-2 agg

  zero_kernel<<<(N_NODES + 255) / 256, 256, 0, stream>>>(cnt, cnt2);
  hist_kernel<<<(EL + 255) / 256, 256, 0, stream>>>(edges, cnt);
  scan_kernel<<<1, 1024, 0, stream>>>(cnt, off);
  scatter_kernel<<<(EL + 255) / 256, 256, 0, stream>>>(edges, off, cnt2, ssrc);

  // weight transpose+convert (per call; cheap)
  convw_kernel<<<(256 * 32 + 255) / 256, 256, 0, stream>>>(gat_w[0], bt0, 64);
  convw_kernel<<<(256 * 128 + 255) / 256, 256, 0, stream>>>(gat_w[1], bt1, 256);
  convw_kernel<<<(256 * 128 + 255) / 256, 256, 0, stream>>>(gat_w[2], bt2, 256);

  const int gblk = N_NODES / 16;      // 625
  const int nblk = N_NODES / 4;       // 2500

  // h0 = relu(x @ lin_w + lin_b)
  gemm_kernel<64, 64, 2><<<gblk, 256, 0, stream>>>(x, lin_w, lin_b, h0);

  // layer 0
  gemm_attn_mfma<64><<<gblk, 256, 0, stream>>>(h0, bt0, xb, att_s[0], att_d[0], as4, ad4);
  agg_kernel<0><<<nblk, 256, 0, stream>>>(off, ssrc, as4, ad4, xb, gat_b[0], h0,
                                          ln_g[0], ln_b[0], hA);
  // layer 1
  gemm_attn_mfma<256><<<gblk, 256, 0, stream>>>(hA, bt1, xb, att_s[1], att_d[1], as4, ad4);
  agg_kernel<1><<<nblk, 256, 0, stream>>>(off, ssrc, as4, ad4, xb, gat_b[1], hA,
                                          ln_g[1], ln_b[1], hB);
  // layer 2
  gemm_attn_mfma<256><<<gblk, 256, 0, stream>>>(hB, bt2, xb, att_s[2], att_d[2], as4, ad4);
  agg_kernel<1><<<nblk, 256, 0, stream>>>(off, ssrc, as4, ad4, xb, gat_b[2], hB,
                                          ln_g[2], ln_b[2], hA);

  // FFN
  gemm_kernel<256, 128, 2><<<gblk, 256, 0, stream>>>(hA, ffn_w1, ffn_b1, mid);
  gemm_kernel<128, 64, 1><<<gblk, 256, 0, stream>>>(mid, ffn_w2, ffn_b2, (float*)d_out);
}

// Round 11
// 165.473 us; speedup vs baseline: 2.5105x; 1.2690x over previous
//
#include <hip/hip_runtime.h>

#define N_NODES 10000
#define N_EDGES 320000
#define EL (N_EDGES + N_NODES)
#define HC 256
#define CAP 96

using bf16x8 = __attribute__((ext_vector_type(8))) short;
using f32x4  = __attribute__((ext_vector_type(4))) float;

__device__ __forceinline__ float bf2f(unsigned short u) {
  union { unsigned int i; float f; } v; v.i = ((unsigned int)u) << 16; return v.f;
}
__device__ __forceinline__ unsigned short f2bf(float f) {
  union { float f; unsigned int i; } v; v.f = f;
  unsigned int r = (v.i + 0x7FFFu + ((v.i >> 16) & 1u)) >> 16;
  return (unsigned short)r;
}

// ---------------- prep: zero degree counters + transpose/convert 3 weight mats ----------
// blocks 0..39: zero cnt; 40..71: convw layer0 (K=64); 72..199: layer1; 200..327: layer2

__device__ __forceinline__ void convw_body(const float* __restrict__ w,
                                           unsigned short* __restrict__ bt,
                                           int K, int idx) {
  int half = K >> 1;
  if (idx >= 256 * half) return;
  int col = idx / half;
  int k2 = (idx % half) * 2;
  ushort2 o;
  o.x = f2bf(w[(size_t)k2 * 256 + col]);
  o.y = f2bf(w[(size_t)(k2 + 1) * 256 + col]);
  *(ushort2*)(bt + (size_t)col * K + k2) = o;
}

__global__ __launch_bounds__(256) void prep_kernel(
    int* __restrict__ cnt,
    const float* __restrict__ w0, unsigned short* __restrict__ bt0,
    const float* __restrict__ w1, unsigned short* __restrict__ bt1,
    const float* __restrict__ w2, unsigned short* __restrict__ bt2) {
  int b = blockIdx.x, tid = threadIdx.x;
  if (b < 40) {
    int i = b * 256 + tid;
    if (i < N_NODES) cnt[i] = 0;
  } else if (b < 72) {
    convw_body(w0, bt0, 64, (b - 40) * 256 + tid);
  } else if (b < 200) {
    convw_body(w1, bt1, 256, (b - 72) * 256 + tid);
  } else {
    convw_body(w2, bt2, 256, (b - 200) * 256 + tid);
  }
}

// ---------------- scatter (buckets) + lin GEMM fused (independent work) ----------------
// blocks 0..1289: scatter edges into slots[d][CAP]; blocks 1290..1914: lin gemm tiles

__global__ __launch_bounds__(256) void scatter_lin_kernel(
    const int* __restrict__ edges, int* __restrict__ cnt, int* __restrict__ slots,
    const float* __restrict__ A, const float* __restrict__ B,
    const float* __restrict__ bias, float* __restrict__ C) {
  int tid = threadIdx.x;
  if (blockIdx.x < 1290) {
    int e = blockIdx.x * 256 + tid;
    if (e >= EL) return;
    int s, d;
    if (e < N_EDGES) { s = edges[e]; d = edges[N_EDGES + e]; }
    else { s = d = e - N_EDGES; }
    int pos = atomicAdd(&cnt[d], 1);
    slots[d * CAP + pos] = s;
    return;
  }
  // lin: h0[row][64] = relu(x[row][64] @ lin_w + lin_b), 16 rows/block
  __shared__ float As[16][36];
  __shared__ float Bs[32][64];
  int row0 = (blockIdx.x - 1290) * 16;
  int g = tid >> 6, lane = tid & 63;
  float acc[4];
#pragma unroll
  for (int r = 0; r < 4; ++r) acc[r] = 0.f;
  for (int k0 = 0; k0 < 64; k0 += 32) {
    if (tid < 128) {
      int r = tid >> 3;
      int kc = (tid & 7) << 2;
      *(float4*)&As[r][kc] = *(const float4*)(A + (size_t)(row0 + r) * 64 + k0 + kc);
    }
    {
      int idx = tid * 2;           // 32*64/256 = 8 floats = 2 per thread? 2048/256=8 -> float2*... use 8 floats via 2 float4s
      // stage 32x64 = 2048 floats with 256 threads: 8 each = 2 float4
#pragma unroll
      for (int i = 0; i < 2; ++i) {
        int fidx = (i * 256 + tid) * 4;
        int kk = fidx >> 6;
        int cc = fidx & 63;
        *(float4*)&Bs[kk][cc] = *(const float4*)(B + (size_t)(k0 + kk) * 64 + cc);
      }
      (void)idx;
    }
    __syncthreads();
#pragma unroll
    for (int kk = 0; kk < 32; kk += 4) {
      float a4[4][4];
#pragma unroll
      for (int rr = 0; rr < 4; ++rr) {
        float4 t = *(const float4*)&As[g * 4 + rr][kk];
        a4[rr][0] = t.x; a4[rr][1] = t.y; a4[rr][2] = t.z; a4[rr][3] = t.w;
      }
#pragma unroll
      for (int u = 0; u < 4; ++u) {
        float b = Bs[kk + u][lane];
#pragma unroll
        for (int rr = 0; rr < 4; ++rr) acc[rr] = fmaf(a4[rr][u], b, acc[rr]);
      }
    }
    __syncthreads();
  }
#pragma unroll
  for (int rr = 0; rr < 4; ++rr) {
    int row = row0 + g * 4 + rr;
    C[(size_t)row * 64 + lane] = fmaxf(acc[rr] + bias[lane], 0.f);
  }
}

// ---------------- MFMA GEMM (attn layers): Cb[M][256] bf16 = A[M][K] @ W, + attn dots ----

template <int K>
__global__ __launch_bounds__(256) void gemm_attn_mfma(
    const float* __restrict__ A, const unsigned short* __restrict__ Bt,
    unsigned short* __restrict__ Cb,
    const float* __restrict__ att_src, const float* __restrict__ att_dst,
    float* __restrict__ asrc_out, float* __restrict__ adst_out) {
  __shared__ __align__(16) unsigned short Asw[16 * 64];
  __shared__ __align__(16) unsigned short Bsw[256 * 64];
  int tid = threadIdx.x;
  int wave = tid >> 6, lane = tid & 63;
  int r = lane & 15, g = lane >> 4;
  int row0 = blockIdx.x * 16;

  f32x4 acc[4];
#pragma unroll
  for (int i = 0; i < 4; ++i) acc[i] = {0.f, 0.f, 0.f, 0.f};

  for (int k0 = 0; k0 < K; k0 += 64) {
    {
      int ar = tid >> 4;
      int kc = (tid & 15) << 2;
      float4 av = *(const float4*)(A + (size_t)(row0 + ar) * K + k0 + kc);
      ushort4 o;
      o.x = f2bf(av.x); o.y = f2bf(av.y); o.z = f2bf(av.z); o.w = f2bf(av.w);
      *(ushort4*)((char*)Asw + ((ar * 128 + kc * 2) ^ ((ar & 7) << 4))) = o;
    }
#pragma unroll
    for (int i = 0; i < 8; ++i) {
      int idx = i * 256 + tid;
      int col = idx >> 3;
      int kc8 = idx & 7;
      uint4 v = *(const uint4*)(Bt + (size_t)col * K + k0 + kc8 * 8);
      *(uint4*)((char*)Bsw + ((col * 128 + kc8 * 16) ^ ((col & 7) << 4))) = v;
    }
    __syncthreads();
#pragma unroll
    for (int chunk = 0; chunk < 2; ++chunk) {
      bf16x8 af = *(const bf16x8*)((char*)Asw +
                    ((r * 128 + chunk * 64 + g * 16) ^ ((r & 7) << 4)));
#pragma unroll
      for (int i = 0; i < 4; ++i) {
        int col = (wave * 4 + i) * 16 + r;
        bf16x8 bfr = *(const bf16x8*)((char*)Bsw +
                       ((col * 128 + chunk * 64 + g * 16) ^ ((col & 7) << 4)));
        acc[i] = __builtin_amdgcn_mfma_f32_16x16x32_bf16(af, bfr, acc[i], 0, 0, 0);
      }
    }
    __syncthreads();
  }

  float asv[4], adv[4];
#pragma unroll
  for (int i = 0; i < 4; ++i) {
    int col = (wave * 4 + i) * 16 + r;
    asv[i] = att_src[col];
    adv[i] = att_dst[col];
  }
#pragma unroll
  for (int j = 0; j < 4; ++j) {
    float ps = acc[0][j] * asv[0] + acc[1][j] * asv[1] + acc[2][j] * asv[2] + acc[3][j] * asv[3];
    float pd = acc[0][j] * adv[0] + acc[1][j] * adv[1] + acc[2][j] * adv[2] + acc[3][j] * adv[3];
#pragma unroll
    for (int m = 8; m >= 1; m >>= 1) {
      ps += __shfl_xor(ps, m);
      pd += __shfl_xor(pd, m);
    }
    if (r == 0) {
      int row = row0 + g * 4 + j;
      asrc_out[row * 4 + wave] = ps;
      adst_out[row * 4 + wave] = pd;
    }
  }

#pragma unroll
  for (int i = 0; i < 4; ++i) {
    int col = (wave * 4 + i) * 16 + r;
#pragma unroll
    for (int j = 0; j < 4; ++j) {
      int row = row0 + g * 4 + j;
      Cb[(size_t)row * 256 + col] = f2bf(acc[i][j]);
    }
  }
}

// ---------------- fused GAT aggregation + bias + ELU + residual + LayerNorm ----------------
// bucket CSR: node n's sources at slots[n*CAP .. n*CAP+cnt[n])

template <int MODE>
__global__ __launch_bounds__(256) void agg_kernel(
    const int* __restrict__ cnt, const int* __restrict__ slots,
    const float* __restrict__ asrc, const float* __restrict__ adst,
    const unsigned short* __restrict__ xb, const float* __restrict__ bias,
    const float* __restrict__ resid, const float* __restrict__ ln_g,
    const float* __restrict__ ln_b, float* __restrict__ hout) {
  int w = threadIdx.x >> 6, lane = threadIdx.x & 63;
  int n = blockIdx.x * 4 + w;
  int h = lane >> 4;
  int ch = lane << 2;
  float ad = adst[n * 4 + h];

  int i0 = n * CAP, i1 = i0 + cnt[n];
  int last = i1 - 1;

  float4 acc = make_float4(0.f, 0.f, 0.f, 0.f);
  float wsum = 0.f;

  int sA[4];
#pragma unroll
  for (int j = 0; j < 4; ++j) sA[j] = slots[min(i0 + j, last)];
  float ca[4]; ushort4 cx[4];
#pragma unroll
  for (int j = 0; j < 4; ++j) {
    ca[j] = asrc[sA[j] * 4 + h];
    cx[j] = *(const ushort4*)(xb + (size_t)sA[j] * HC + ch);
  }
#pragma unroll
  for (int j = 0; j < 4; ++j) sA[j] = slots[min(i0 + 4 + j, last)];

#pragma unroll 2
  for (int base = i0; base < i1; base += 4) {
    float na[4]; ushort4 nx[4];
#pragma unroll
    for (int j = 0; j < 4; ++j) {
      na[j] = asrc[sA[j] * 4 + h];
      nx[j] = *(const ushort4*)(xb + (size_t)sA[j] * HC + ch);
    }
#pragma unroll
    for (int j = 0; j < 4; ++j) sA[j] = slots[min(base + 8 + j, last)];
#pragma unroll
    for (int j = 0; j < 4; ++j) {
      float e = ca[j] + ad;
      e = e > 0.f ? e : 0.2f * e;
      float wg = __expf(e);
      wg = (base + j < i1) ? wg : 0.f;
      wsum += wg;
      acc.x = fmaf(wg, bf2f(cx[j].x), acc.x);
      acc.y = fmaf(wg, bf2f(cx[j].y), acc.y);
      acc.z = fmaf(wg, bf2f(cx[j].z), acc.z);
      acc.w = fmaf(wg, bf2f(cx[j].w), acc.w);
    }
#pragma unroll
    for (int j = 0; j < 4; ++j) { ca[j] = na[j]; cx[j] = nx[j]; }
  }

  float rw = 1.f / wsum;
  float4 b4 = *(const float4*)(bias + ch);
  float v0 = fmaf(acc.x, rw, b4.x);
  float v1 = fmaf(acc.y, rw, b4.y);
  float v2 = fmaf(acc.z, rw, b4.z);
  float v3 = fmaf(acc.w, rw, b4.w);
  v0 = v0 > 0.f ? v0 : __expf(v0) - 1.f;
  v1 = v1 > 0.f ? v1 : __expf(v1) - 1.f;
  v2 = v2 > 0.f ? v2 : __expf(v2) - 1.f;
  v3 = v3 > 0.f ? v3 : __expf(v3) - 1.f;

  if constexpr (MODE == 0) {
    if (lane < 16) {
      float4 r = *(const float4*)(resid + (size_t)n * 64 + ch);
      v0 += r.x; v1 += r.y; v2 += r.z; v3 += r.w;
    }
  } else {
    float4 r = *(const float4*)(resid + (size_t)n * HC + ch);
    v0 += r.x; v1 += r.y; v2 += r.z; v3 += r.w;
  }

  float s1 = v0 + v1 + v2 + v3;
  float s2 = v0 * v0 + v1 * v1 + v2 * v2 + v3 * v3;
#pragma unroll
  for (int m = 32; m >= 1; m >>= 1) {
    s1 += __shfl_xor(s1, m);
    s2 += __shfl_xor(s2, m);
  }
  float mean = s1 * (1.f / 256.f);
  float var = s2 * (1.f / 256.f) - mean * mean;
  float inv = rsqrtf(var + 1e-5f);

  float4 g4 = *(const float4*)(ln_g + ch);
  float4 lb4 = *(const float4*)(ln_b + ch);
  float4 o;
  o.x = (v0 - mean) * inv * g4.x + lb4.x;
  o.y = (v1 - mean) * inv * g4.y + lb4.y;
  o.z = (v2 - mean) * inv * g4.z + lb4.z;
  o.w = (v3 - mean) * inv * g4.w + lb4.w;
  *(float4*)(hout + (size_t)n * HC + ch) = o;
}

// ---------------- fused FFN: out = relu(hA@w1+b1)@w2 + b2, mid kept in LDS -------------

__global__ __launch_bounds__(256) void ffn_kernel(const float* __restrict__ A,
                                                  const float* __restrict__ w1,
                                                  const float* __restrict__ b1,
                                                  const float* __restrict__ w2,
                                                  const float* __restrict__ b2,
                                                  float* __restrict__ out) {
  __shared__ float As[16][36];
  __shared__ float Bs[32][128];
  __shared__ float Ms[16][132];
  int tid = threadIdx.x;
  int row0 = blockIdx.x * 16;
  int g = tid >> 6, lane = tid & 63;

  // phase 1: mid[16][128] = relu(A[16][256] @ w1 + b1)
  {
    int colBase = lane * 2;
    float acc[4][2];
#pragma unroll
    for (int r = 0; r < 4; ++r) { acc[r][0] = 0.f; acc[r][1] = 0.f; }
    for (int k0 = 0; k0 < 256; k0 += 32) {
      if (tid < 128) {
        int r = tid >> 3;
        int kc = (tid & 7) << 2;
        *(float4*)&As[r][kc] = *(const float4*)(A + (size_t)(row0 + r) * 256 + k0 + kc);
      }
#pragma unroll
      for (int i = 0; i < 4; ++i) {  // 32*128 floats / 256 threads = 16 = 4 float4
        int fidx = (i * 256 + tid) * 4;
        int kk = fidx >> 7;
        int cc = fidx & 127;
        *(float4*)&Bs[kk][cc] = *(const float4*)(w1 + (size_t)(k0 + kk) * 128 + cc);
      }
      __syncthreads();
#pragma unroll
      for (int kk = 0; kk < 32; kk += 4) {
        float a4[4][4];
#pragma unroll
        for (int rr = 0; rr < 4; ++rr) {
          float4 t = *(const float4*)&As[g * 4 + rr][kk];
          a4[rr][0] = t.x; a4[rr][1] = t.y; a4[rr][2] = t.z; a4[rr][3] = t.w;
        }
#pragma unroll
        for (int u = 0; u < 4; ++u) {
          float2 b = *(const float2*)&Bs[kk + u][colBase];
#pragma unroll
          for (int rr = 0; rr < 4; ++rr) {
            acc[rr][0] = fmaf(a4[rr][u], b.x, acc[rr][0]);
            acc[rr][1] = fmaf(a4[rr][u], b.y, acc[rr][1]);
          }
        }
      }
      __syncthreads();
    }
    float bb0 = b1[colBase], bb1 = b1[colBase + 1];
#pragma unroll
    for (int rr = 0; rr < 4; ++rr) {
      Ms[g * 4 + rr][colBase]     = fmaxf(acc[rr][0] + bb0, 0.f);
      Ms[g * 4 + rr][colBase + 1] = fmaxf(acc[rr][1] + bb1, 0.f);
    }
  }
  __syncthreads();

  // phase 2: out[16][64] = Ms[16][128] @ w2 + b2
  {
    float acc[4];
#pragma unroll
    for (int r = 0; r < 4; ++r) acc[r] = 0.f;
    for (int k0 = 0; k0 < 128; k0 += 32) {
#pragma unroll
      for (int i = 0; i < 2; ++i) {  // 32*64 floats / 256 = 8 = 2 float4 (reuse Bs cols 0..63)
        int fidx = (i * 256 + tid) * 4;
        int kk = fidx >> 6;
        int cc = fidx & 63;
        *(float4*)&Bs[kk][cc] = *(const float4*)(w2 + (size_t)(k0 + kk) * 64 + cc);
      }
      __syncthreads();
#pragma unroll
      for (int kk = 0; kk < 32; ++kk) {
        float b = Bs[kk][lane];
#pragma unroll
        for (int rr = 0; rr < 4; ++rr)
          acc[rr] = fmaf(Ms[g * 4 + rr][k0 + kk], b, acc[rr]);
      }
      __syncthreads();
    }
    float bb = b2[lane];
#pragma unroll
    for (int rr = 0; rr < 4; ++rr) {
      int row = row0 + g * 4 + rr;
      out[(size_t)row * 64 + lane] = acc[rr] + bb;
    }
  }
}

// ---------------- launch ----------------

extern "C" void kernel_launch(void* const* d_in, const int* in_sizes, int n_in,
                              void* d_out, int out_size, void* d_ws, size_t ws_size,
                              hipStream_t stream) {
  (void)in_sizes; (void)n_in; (void)out_size; (void)ws_size;
  const float* x      = (const float*)d_in[0];
  const int*   edges  = (const int*)d_in[1];
  const float* lin_w  = (const float*)d_in[2];
  const float* lin_b  = (const float*)d_in[3];
  const float* gat_w[3] = {(const float*)d_in[4], (const float*)d_in[10], (const float*)d_in[16]};
  const float* att_s[3] = {(const float*)d_in[5], (const float*)d_in[11], (const float*)d_in[17]};
  const float* att_d[3] = {(const float*)d_in[6], (const float*)d_in[12], (const float*)d_in[18]};
  const float* gat_b[3] = {(const float*)d_in[7], (const float*)d_in[13], (const float*)d_in[19]};
  const float* ln_g[3]  = {(const float*)d_in[8], (const float*)d_in[14], (const float*)d_in[20]};
  const float* ln_b[3]  = {(const float*)d_in[9], (const float*)d_in[15], (const float*)d_in[21]};
  const float* ffn_w1 = (const float*)d_in[22];
  const float* ffn_b1 = (const float*)d_in[23];
  const float* ffn_w2 = (const float*)d_in[24];
  const float* ffn_b2 = (const float*)d_in[25];

  char* p = (char*)d_ws;
  auto alloc = [&](size_t bytes) {
    char* q = p;
    p += (bytes + 255) & ~(size_t)255;
    return q;
  };
  int* cnt   = (int*)alloc(N_NODES * 4);
  int* slots = (int*)alloc((size_t)N_NODES * CAP * 4);
  float* h0  = (float*)alloc((size_t)N_NODES * 64 * 4);
  float* hA  = (float*)alloc((size_t)N_NODES * HC * 4);
  float* hB  = (float*)alloc((size_t)N_NODES * HC * 4);
  unsigned short* xb = (unsigned short*)alloc((size_t)N_NODES * HC * 2);
  float* as4 = (float*)alloc((size_t)N_NODES * 16);
  float* ad4 = (float*)alloc((size_t)N_NODES * 16);
  unsigned short* bt0 = (unsigned short*)alloc(256 * 64 * 2);
  unsigned short* bt1 = (unsigned short*)alloc(256 * 256 * 2);
  unsigned short* bt2 = (unsigned short*)alloc(256 * 256 * 2);

  const int gblk = N_NODES / 16;      // 625
  const int nblk = N_NODES / 4;       // 2500

  // 1: zero counters + convert 3 weight matrices
  prep_kernel<<<328, 256, 0, stream>>>(cnt, gat_w[0], bt0, gat_w[1], bt1, gat_w[2], bt2);
  // 2: bucket scatter + lin GEMM (independent)
  scatter_lin_kernel<<<1290 + 625, 256, 0, stream>>>(edges, cnt, slots, x, lin_w, lin_b, h0);

  // layer 0
  gemm_attn_mfma<64><<<gblk, 256, 0, stream>>>(h0, bt0, xb, att_s[0], att_d[0], as4, ad4);
  agg_kernel<0><<<nblk, 256, 0, stream>>>(cnt, slots, as4, ad4, xb, gat_b[0], h0,
                                          ln_g[0], ln_b[0], hA);
  // layer 1
  gemm_attn_mfma<256><<<gblk, 256, 0, stream>>>(hA, bt1, xb, att_s[1], att_d[1], as4, ad4);
  agg_kernel<1><<<nblk, 256, 0, stream>>>(cnt, slots, as4, ad4, xb, gat_b[1], hA,
                                          ln_g[1], ln_b[1], hB);
  // layer 2
  gemm_attn_mfma<256><<<gblk, 256, 0, stream>>>(hB, bt2, xb, att_s[2], att_d[2], as4, ad4);
  agg_kernel<1><<<nblk, 256, 0, stream>>>(cnt, slots, as4, ad4, xb, gat_b[2], hB,
                                          ln_g[2], ln_b[2], hA);

  // fused FFN
  ffn_kernel<<<gblk, 256, 0, stream>>>(hA, ffn_w1, ffn_b1, ffn_w2, ffn_b2, (float*)d_out);
}

// Round 14
// 153.893 us; speedup vs baseline: 2.6994x; 1.0752x over previous
//
#include <hip/hip_runtime.h>

#define N_NODES 10000
#define N_EDGES 320000
#define EL (N_EDGES + N_NODES)
#define HC 256
#define CAP 96

using bf16x8 = __attribute__((ext_vector_type(8))) short;
using f32x4  = __attribute__((ext_vector_type(4))) float;

__device__ __forceinline__ float bf2f(unsigned short u) {
  union { unsigned int i; float f; } v; v.i = ((unsigned int)u) << 16; return v.f;
}
__device__ __forceinline__ unsigned short f2bf(float f) {
  union { float f; unsigned int i; } v; v.f = f;
  unsigned int r = (v.i + 0x7FFFu + ((v.i >> 16) & 1u)) >> 16;
  return (unsigned short)r;
}

// ---------------- prep: zero degree counters + transpose/convert 3 weight mats ----------

__device__ __forceinline__ void convw_body(const float* __restrict__ w,
                                           unsigned short* __restrict__ bt,
                                           int K, int idx) {
  int half = K >> 1;
  if (idx >= 256 * half) return;
  int col = idx / half;
  int k2 = (idx % half) * 2;
  ushort2 o;
  o.x = f2bf(w[(size_t)k2 * 256 + col]);
  o.y = f2bf(w[(size_t)(k2 + 1) * 256 + col]);
  *(ushort2*)(bt + (size_t)col * K + k2) = o;
}

__global__ __launch_bounds__(256) void prep_kernel(
    int* __restrict__ cnt,
    const float* __restrict__ w0, unsigned short* __restrict__ bt0,
    const float* __restrict__ w1, unsigned short* __restrict__ bt1,
    const float* __restrict__ w2, unsigned short* __restrict__ bt2) {
  int b = blockIdx.x, tid = threadIdx.x;
  if (b < 40) {
    int i = b * 256 + tid;
    if (i < N_NODES) cnt[i] = 0;
  } else if (b < 72) {
    convw_body(w0, bt0, 64, (b - 40) * 256 + tid);
  } else if (b < 200) {
    convw_body(w1, bt1, 256, (b - 72) * 256 + tid);
  } else {
    convw_body(w2, bt2, 256, (b - 200) * 256 + tid);
  }
}

// ---------------- scatter (buckets) + lin GEMM fused (independent work) ----------------

__global__ __launch_bounds__(256) void scatter_lin_kernel(
    const int* __restrict__ edges, int* __restrict__ cnt, int* __restrict__ slots,
    const float* __restrict__ A, const float* __restrict__ B,
    const float* __restrict__ bias, float* __restrict__ C) {
  int tid = threadIdx.x;
  if (blockIdx.x < 1290) {
    int e = blockIdx.x * 256 + tid;
    if (e >= EL) return;
    int s, d;
    if (e < N_EDGES) { s = edges[e]; d = edges[N_EDGES + e]; }
    else { s = d = e - N_EDGES; }
    int pos = atomicAdd(&cnt[d], 1);
    slots[d * CAP + pos] = s;
    return;
  }
  __shared__ float As[16][36];
  __shared__ float Bs[32][64];
  int row0 = (blockIdx.x - 1290) * 16;
  int g = tid >> 6, lane = tid & 63;
  float acc[4];
#pragma unroll
  for (int r = 0; r < 4; ++r) acc[r] = 0.f;
  for (int k0 = 0; k0 < 64; k0 += 32) {
    if (tid < 128) {
      int r = tid >> 3;
      int kc = (tid & 7) << 2;
      *(float4*)&As[r][kc] = *(const float4*)(A + (size_t)(row0 + r) * 64 + k0 + kc);
    }
    {
#pragma unroll
      for (int i = 0; i < 2; ++i) {
        int fidx = (i * 256 + tid) * 4;
        int kk = fidx >> 6;
        int cc = fidx & 63;
        *(float4*)&Bs[kk][cc] = *(const float4*)(B + (size_t)(k0 + kk) * 64 + cc);
      }
    }
    __syncthreads();
#pragma unroll
    for (int kk = 0; kk < 32; kk += 4) {
      float a4[4][4];
#pragma unroll
      for (int rr = 0; rr < 4; ++rr) {
        float4 t = *(const float4*)&As[g * 4 + rr][kk];
        a4[rr][0] = t.x; a4[rr][1] = t.y; a4[rr][2] = t.z; a4[rr][3] = t.w;
      }
#pragma unroll
      for (int u = 0; u < 4; ++u) {
        float b = Bs[kk + u][lane];
#pragma unroll
        for (int rr = 0; rr < 4; ++rr) acc[rr] = fmaf(a4[rr][u], b, acc[rr]);
      }
    }
    __syncthreads();
  }
#pragma unroll
  for (int rr = 0; rr < 4; ++rr) {
    int row = row0 + g * 4 + rr;
    C[(size_t)row * 64 + lane] = fmaxf(acc[rr] + bias[lane], 0.f);
  }
}

// ---------------- MFMA GEMM (attn layers): Cb[M][256] bf16 = A[M][K] @ W, + attn dots ----

template <int K>
__global__ __launch_bounds__(256) void gemm_attn_mfma(
    const float* __restrict__ A, const unsigned short* __restrict__ Bt,
    unsigned short* __restrict__ Cb,
    const float* __restrict__ att_src, const float* __restrict__ att_dst,
    float* __restrict__ asrc_out, float* __restrict__ adst_out) {
  __shared__ __align__(16) unsigned short Asw[16 * 64];
  __shared__ __align__(16) unsigned short Bsw[256 * 64];
  int tid = threadIdx.x;
  int wave = tid >> 6, lane = tid & 63;
  int r = lane & 15, g = lane >> 4;
  int row0 = blockIdx.x * 16;

  f32x4 acc[4];
#pragma unroll
  for (int i = 0; i < 4; ++i) acc[i] = {0.f, 0.f, 0.f, 0.f};

  for (int k0 = 0; k0 < K; k0 += 64) {
    {
      int ar = tid >> 4;
      int kc = (tid & 15) << 2;
      float4 av = *(const float4*)(A + (size_t)(row0 + ar) * K + k0 + kc);
      ushort4 o;
      o.x = f2bf(av.x); o.y = f2bf(av.y); o.z = f2bf(av.z); o.w = f2bf(av.w);
      *(ushort4*)((char*)Asw + ((ar * 128 + kc * 2) ^ ((ar & 7) << 4))) = o;
    }
#pragma unroll
    for (int i = 0; i < 8; ++i) {
      int idx = i * 256 + tid;
      int col = idx >> 3;
      int kc8 = idx & 7;
      uint4 v = *(const uint4*)(Bt + (size_t)col * K + k0 + kc8 * 8);
      *(uint4*)((char*)Bsw + ((col * 128 + kc8 * 16) ^ ((col & 7) << 4))) = v;
    }
    __syncthreads();
#pragma unroll
    for (int chunk = 0; chunk < 2; ++chunk) {
      bf16x8 af = *(const bf16x8*)((char*)Asw +
                    ((r * 128 + chunk * 64 + g * 16) ^ ((r & 7) << 4)));
#pragma unroll
      for (int i = 0; i < 4; ++i) {
        int col = (wave * 4 + i) * 16 + r;
        bf16x8 bfr = *(const bf16x8*)((char*)Bsw +
                       ((col * 128 + chunk * 64 + g * 16) ^ ((col & 7) << 4)));
        acc[i] = __builtin_amdgcn_mfma_f32_16x16x32_bf16(af, bfr, acc[i], 0, 0, 0);
      }
    }
    __syncthreads();
  }

  float asv[4], adv[4];
#pragma unroll
  for (int i = 0; i < 4; ++i) {
    int col = (wave * 4 + i) * 16 + r;
    asv[i] = att_src[col];
    adv[i] = att_dst[col];
  }
#pragma unroll
  for (int j = 0; j < 4; ++j) {
    float ps = acc[0][j] * asv[0] + acc[1][j] * asv[1] + acc[2][j] * asv[2] + acc[3][j] * asv[3];
    float pd = acc[0][j] * adv[0] + acc[1][j] * adv[1] + acc[2][j] * adv[2] + acc[3][j] * adv[3];
#pragma unroll
    for (int m = 8; m >= 1; m >>= 1) {
      ps += __shfl_xor(ps, m);
      pd += __shfl_xor(pd, m);
    }
    if (r == 0) {
      int row = row0 + g * 4 + j;
      asrc_out[row * 4 + wave] = ps;
      adst_out[row * 4 + wave] = pd;
    }
  }

#pragma unroll
  for (int i = 0; i < 4; ++i) {
    int col = (wave * 4 + i) * 16 + r;
#pragma unroll
    for (int j = 0; j < 4; ++j) {
      int row = row0 + g * 4 + j;
      Cb[(size_t)row * 256 + col] = f2bf(acc[i][j]);
    }
  }
}

// ---------------- fused GAT aggregation + bias + ELU + residual + LayerNorm ----------------
// Half-wave edge parallelism: lanes 0-31 process first half of edge list, lanes 32-63
// second half; each lane gathers 8 channels (16B bf16). Combine via shfl_xor(32); then
// lane owns 4 channels (cb = (lane&31)*8 + (lane>>5)*4) for epilogue.

template <int MODE>
__global__ __launch_bounds__(256) void agg_kernel(
    const int* __restrict__ cnt, const int* __restrict__ slots,
    const float* __restrict__ asrc, const float* __restrict__ adst,
    const unsigned short* __restrict__ xb, const float* __restrict__ bias,
    const float* __restrict__ resid, const float* __restrict__ ln_g,
    const float* __restrict__ ln_b, float* __restrict__ hout) {
  int w = threadIdx.x >> 6, lane = threadIdx.x & 63;
  int n = blockIdx.x * 4 + w;
  int lh = lane & 31;
  int half = lane >> 5;
  int h = lh >> 3;
  int ch8 = lh << 3;
  float ad = adst[n * 4 + h];

  int i0 = n * CAP;
  int deg = cnt[n];
  int len0 = (deg + 1) >> 1;
  int beg = i0 + (half ? len0 : 0);
  int end = i0 + (half ? deg : len0);
  int last = end - 1;  // >= i0 always (deg>=1 from self-loop); valid even if half empty

  float a0 = 0.f, a1 = 0.f, a2 = 0.f, a3 = 0.f, a4 = 0.f, a5 = 0.f, a6 = 0.f, a7 = 0.f;
  float wsum = 0.f;

  int sA[4];
#pragma unroll
  for (int j = 0; j < 4; ++j) sA[j] = slots[min(beg + j, last)];
  float ca[4]; uint4 cx[4];
#pragma unroll
  for (int j = 0; j < 4; ++j) {
    ca[j] = asrc[sA[j] * 4 + h];
    cx[j] = *(const uint4*)(xb + (size_t)sA[j] * HC + ch8);
  }
#pragma unroll
  for (int j = 0; j < 4; ++j) sA[j] = slots[min(beg + 4 + j, last)];

  for (int base = beg; base < end; base += 4) {
    float na[4]; uint4 nx[4];
#pragma unroll
    for (int j = 0; j < 4; ++j) {
      na[j] = asrc[sA[j] * 4 + h];
      nx[j] = *(const uint4*)(xb + (size_t)sA[j] * HC + ch8);
    }
#pragma unroll
    for (int j = 0; j < 4; ++j) sA[j] = slots[min(base + 8 + j, last)];
#pragma unroll
    for (int j = 0; j < 4; ++j) {
      float e = ca[j] + ad;
      e = e > 0.f ? e : 0.2f * e;
      float wg = __expf(e);
      wg = (base + j < end) ? wg : 0.f;
      wsum += wg;
      a0 = fmaf(wg, bf2f((unsigned short)(cx[j].x & 0xffff)), a0);
      a1 = fmaf(wg, bf2f((unsigned short)(cx[j].x >> 16)), a1);
      a2 = fmaf(wg, bf2f((unsigned short)(cx[j].y & 0xffff)), a2);
      a3 = fmaf(wg, bf2f((unsigned short)(cx[j].y >> 16)), a3);
      a4 = fmaf(wg, bf2f((unsigned short)(cx[j].z & 0xffff)), a4);
      a5 = fmaf(wg, bf2f((unsigned short)(cx[j].z >> 16)), a5);
      a6 = fmaf(wg, bf2f((unsigned short)(cx[j].w & 0xffff)), a6);
      a7 = fmaf(wg, bf2f((unsigned short)(cx[j].w >> 16)), a7);
    }
#pragma unroll
    for (int j = 0; j < 4; ++j) { ca[j] = na[j]; cx[j] = nx[j]; }
  }

  // combine halves (lanes l and l+32 hold same channels, different edge subsets)
  a0 += __shfl_xor(a0, 32); a1 += __shfl_xor(a1, 32);
  a2 += __shfl_xor(a2, 32); a3 += __shfl_xor(a3, 32);
  a4 += __shfl_xor(a4, 32); a5 += __shfl_xor(a5, 32);
  a6 += __shfl_xor(a6, 32); a7 += __shfl_xor(a7, 32);
  wsum += __shfl_xor(wsum, 32);

  // lane takes 4 channels: cb = ch8 + half*4
  int cb = ch8 + half * 4;
  float v0 = half ? a4 : a0;
  float v1 = half ? a5 : a1;
  float v2 = half ? a6 : a2;
  float v3 = half ? a7 : a3;

  float rw = 1.f / wsum;
  float4 b4 = *(const float4*)(bias + cb);
  v0 = fmaf(v0, rw, b4.x);
  v1 = fmaf(v1, rw, b4.y);
  v2 = fmaf(v2, rw, b4.z);
  v3 = fmaf(v3, rw, b4.w);
  v0 = v0 > 0.f ? v0 : __expf(v0) - 1.f;
  v1 = v1 > 0.f ? v1 : __expf(v1) - 1.f;
  v2 = v2 > 0.f ? v2 : __expf(v2) - 1.f;
  v3 = v3 > 0.f ? v3 : __expf(v3) - 1.f;

  if constexpr (MODE == 0) {
    if (cb < 64) {
      float4 r = *(const float4*)(resid + (size_t)n * 64 + cb);
      v0 += r.x; v1 += r.y; v2 += r.z; v3 += r.w;
    }
  } else {
    float4 r = *(const float4*)(resid + (size_t)n * HC + cb);
    v0 += r.x; v1 += r.y; v2 += r.z; v3 += r.w;
  }

  float s1 = v0 + v1 + v2 + v3;
  float s2 = v0 * v0 + v1 * v1 + v2 * v2 + v3 * v3;
#pragma unroll
  for (int m = 32; m >= 1; m >>= 1) {
    s1 += __shfl_xor(s1, m);
    s2 += __shfl_xor(s2, m);
  }
  float mean = s1 * (1.f / 256.f);
  float var = s2 * (1.f / 256.f) - mean * mean;
  float inv = rsqrtf(var + 1e-5f);

  float4 g4 = *(const float4*)(ln_g + cb);
  float4 lb4 = *(const float4*)(ln_b + cb);
  float4 o;
  o.x = (v0 - mean) * inv * g4.x + lb4.x;
  o.y = (v1 - mean) * inv * g4.y + lb4.y;
  o.z = (v2 - mean) * inv * g4.z + lb4.z;
  o.w = (v3 - mean) * inv * g4.w + lb4.w;
  *(float4*)(hout + (size_t)n * HC + cb) = o;
}

// ---------------- fused FFN: out = relu(hA@w1+b1)@w2 + b2, mid kept in LDS -------------

__global__ __launch_bounds__(256) void ffn_kernel(const float* __restrict__ A,
                                                  const float* __restrict__ w1,
                                                  const float* __restrict__ b1,
                                                  const float* __restrict__ w2,
                                                  const float* __restrict__ b2,
                                                  float* __restrict__ out) {
  __shared__ float As[16][36];
  __shared__ float Bs[32][128];
  __shared__ float Ms[16][132];
  int tid = threadIdx.x;
  int row0 = blockIdx.x * 16;
  int g = tid >> 6, lane = tid & 63;

  {
    int colBase = lane * 2;
    float acc[4][2];
#pragma unroll
    for (int r = 0; r < 4; ++r) { acc[r][0] = 0.f; acc[r][1] = 0.f; }
    for (int k0 = 0; k0 < 256; k0 += 32) {
      if (tid < 128) {
        int r = tid >> 3;
        int kc = (tid & 7) << 2;
        *(float4*)&As[r][kc] = *(const float4*)(A + (size_t)(row0 + r) * 256 + k0 + kc);
      }
#pragma unroll
      for (int i = 0; i < 4; ++i) {
        int fidx = (i * 256 + tid) * 4;
        int kk = fidx >> 7;
        int cc = fidx & 127;
        *(float4*)&Bs[kk][cc] = *(const float4*)(w1 + (size_t)(k0 + kk) * 128 + cc);
      }
      __syncthreads();
#pragma unroll
      for (int kk = 0; kk < 32; kk += 4) {
        float a4[4][4];
#pragma unroll
        for (int rr = 0; rr < 4; ++rr) {
          float4 t = *(const float4*)&As[g * 4 + rr][kk];
          a4[rr][0] = t.x; a4[rr][1] = t.y; a4[rr][2] = t.z; a4[rr][3] = t.w;
        }
#pragma unroll
        for (int u = 0; u < 4; ++u) {
          float2 b = *(const float2*)&Bs[kk + u][colBase];
#pragma unroll
          for (int rr = 0; rr < 4; ++rr) {
            acc[rr][0] = fmaf(a4[rr][u], b.x, acc[rr][0]);
            acc[rr][1] = fmaf(a4[rr][u], b.y, acc[rr][1]);
          }
        }
      }
      __syncthreads();
    }
    float bb0 = b1[colBase], bb1 = b1[colBase + 1];
#pragma unroll
    for (int rr = 0; rr < 4; ++rr) {
      Ms[g * 4 + rr][colBase]     = fmaxf(acc[rr][0] + bb0, 0.f);
      Ms[g * 4 + rr][colBase + 1] = fmaxf(acc[rr][1] + bb1, 0.f);
    }
  }
  __syncthreads();

  {
    float acc[4];
#pragma unroll
    for (int r = 0; r < 4; ++r) acc[r] = 0.f;
    for (int k0 = 0; k0 < 128; k0 += 32) {
#pragma unroll
      for (int i = 0; i < 2; ++i) {
        int fidx = (i * 256 + tid) * 4;
        int kk = fidx >> 6;
        int cc = fidx & 63;
        *(float4*)&Bs[kk][cc] = *(const float4*)(w2 + (size_t)(k0 + kk) * 64 + cc);
      }
      __syncthreads();
#pragma unroll
      for (int kk = 0; kk < 32; ++kk) {
        float b = Bs[kk][lane];
#pragma unroll
        for (int rr = 0; rr < 4; ++rr)
          acc[rr] = fmaf(Ms[g * 4 + rr][k0 + kk], b, acc[rr]);
      }
      __syncthreads();
    }
    float bb = b2[lane];
#pragma unroll
    for (int rr = 0; rr < 4; ++rr) {
      int row = row0 + g * 4 + rr;
      out[(size_t)row * 64 + lane] = acc[rr] + bb;
    }
  }
}

// ---------------- launch ----------------

extern "C" void kernel_launch(void* const* d_in, const int* in_sizes, int n_in,
                              void* d_out, int out_size, void* d_ws, size_t ws_size,
                              hipStream_t stream) {
  (void)in_sizes; (void)n_in; (void)out_size; (void)ws_size;
  const float* x      = (const float*)d_in[0];
  const int*   edges  = (const int*)d_in[1];
  const float* lin_w  = (const float*)d_in[2];
  const float* lin_b  = (const float*)d_in[3];
  const float* gat_w[3] = {(const float*)d_in[4], (const float*)d_in[10], (const float*)d_in[16]};
  const float* att_s[3] = {(const float*)d_in[5], (const float*)d_in[11], (const float*)d_in[17]};
  const float* att_d[3] = {(const float*)d_in[6], (const float*)d_in[12], (const float*)d_in[18]};
  const float* gat_b[3] = {(const float*)d_in[7], (const float*)d_in[13], (const float*)d_in[19]};
  const float* ln_g[3]  = {(const float*)d_in[8], (const float*)d_in[14], (const float*)d_in[20]};
  const float* ln_b[3]  = {(const float*)d_in[9], (const float*)d_in[15], (const float*)d_in[21]};
  const float* ffn_w1 = (const float*)d_in[22];
  const float* ffn_b1 = (const float*)d_in[23];
  const float* ffn_w2 = (const float*)d_in[24];
  const float* ffn_b2 = (const float*)d_in[25];

  char* p = (char*)d_ws;
  auto alloc = [&](size_t bytes) {
    char* q = p;
    p += (bytes + 255) & ~(size_t)255;
    return q;
  };
  int* cnt   = (int*)alloc(N_NODES * 4);
  int* slots = (int*)alloc((size_t)N_NODES * CAP * 4);
  float* h0  = (float*)alloc((size_t)N_NODES * 64 * 4);
  float* hA  = (float*)alloc((size_t)N_NODES * HC * 4);
  float* hB  = (float*)alloc((size_t)N_NODES * HC * 4);
  unsigned short* xb = (unsigned short*)alloc((size_t)N_NODES * HC * 2);
  float* as4 = (float*)alloc((size_t)N_NODES * 16);
  float* ad4 = (float*)alloc((size_t)N_NODES * 16);
  unsigned short* bt0 = (unsigned short*)alloc(256 * 64 * 2);
  unsigned short* bt1 = (unsigned short*)alloc(256 * 256 * 2);
  unsigned short* bt2 = (unsigned short*)alloc(256 * 256 * 2);

  const int gblk = N_NODES / 16;      // 625
  const int nblk = N_NODES / 4;       // 2500

  prep_kernel<<<328, 256, 0, stream>>>(cnt, gat_w[0], bt0, gat_w[1], bt1, gat_w[2], bt2);
  scatter_lin_kernel<<<1290 + 625, 256, 0, stream>>>(edges, cnt, slots, x, lin_w, lin_b, h0);

  // layer 0
  gemm_attn_mfma<64><<<gblk, 256, 0, stream>>>(h0, bt0, xb, att_s[0], att_d[0], as4, ad4);
  agg_kernel<0><<<nblk, 256, 0, stream>>>(cnt, slots, as4, ad4, xb, gat_b[0], h0,
                                          ln_g[0], ln_b[0], hA);
  // layer 1
  gemm_attn_mfma<256><<<gblk, 256, 0, stream>>>(hA, bt1, xb, att_s[1], att_d[1], as4, ad4);
  agg_kernel<1><<<nblk, 256, 0, stream>>>(cnt, slots, as4, ad4, xb, gat_b[1], hA,
                                          ln_g[1], ln_b[1], hB);
  // layer 2
  gemm_attn_mfma<256><<<gblk, 256, 0, stream>>>(hB, bt2, xb, att_s[2], att_d[2], as4, ad4);
  agg_kernel<1><<<nblk, 256, 0, stream>>>(cnt, slots, as4, ad4, xb, gat_b[2], hB,
                                          ln_g[2], ln_b[2], hA);

  // fused FFN
  ffn_kernel<<<gblk, 256, 0, stream>>>(hA, ffn_w1, ffn_b1, ffn_w2, ffn_b2, (float*)d_out);
}